// Round 1
// baseline (11945.554 us; speedup 1.0000x reference)
//
#include <hip/hip_runtime.h>
#include <math.h>

#define SEQ  512
#define PREV 512
#define TOT  1024
#define BSZ  8
#define DIN  1024
#define NH   16
#define HD   64

// ---------------------------------------------------------------------------
// f32 tiled GEMM: C = A @ B (+ R), all row-major. M,N multiples of 128; K mult of 16.
// 256 threads, BM=BN=128, BK=16, each thread owns 2x2 blocks of 4x4.
// ---------------------------------------------------------------------------
__global__ __launch_bounds__(256) void gemm_f32(
    const float* __restrict__ A, const float* __restrict__ B,
    const float* __restrict__ R, float* __restrict__ C,
    int M, int N, int K)
{
    __shared__ float As[16][132];   // transposed: As[k][m], padded (132*4B = 16B-mult)
    __shared__ float Bs[16][132];   // Bs[k][n]

    const int t  = threadIdx.x;
    const int tx = t & 15, ty = t >> 4;
    const int bm = blockIdx.y * 128, bn = blockIdx.x * 128;

    float acc[2][2][4][4];
#pragma unroll
    for (int i = 0; i < 2; ++i)
#pragma unroll
      for (int j = 0; j < 2; ++j)
#pragma unroll
        for (int r = 0; r < 4; ++r)
#pragma unroll
          for (int c = 0; c < 4; ++c) acc[i][j][r][c] = 0.f;

    for (int k0 = 0; k0 < K; k0 += 16) {
#pragma unroll
        for (int e = 0; e < 2; ++e) {
            int lin = t + e * 256;                 // 512 float4 for A, 512 for B
            int arow = lin >> 2, ac4 = (lin & 3) * 4;
            float4 a4 = *(const float4*)(A + (size_t)(bm + arow) * K + k0 + ac4);
            As[ac4 + 0][arow] = a4.x;
            As[ac4 + 1][arow] = a4.y;
            As[ac4 + 2][arow] = a4.z;
            As[ac4 + 3][arow] = a4.w;
            int brow = lin >> 5, bc4 = (lin & 31) * 4;
            *(float4*)&Bs[brow][bc4] =
                *(const float4*)(B + (size_t)(k0 + brow) * N + bn + bc4);
        }
        __syncthreads();
#pragma unroll
        for (int k = 0; k < 16; ++k) {
            float4 a0 = *(float4*)&As[k][ty * 4];
            float4 a1 = *(float4*)&As[k][64 + ty * 4];
            float4 b0 = *(float4*)&Bs[k][tx * 4];
            float4 b1 = *(float4*)&Bs[k][64 + tx * 4];
            float ar[2][4] = {{a0.x, a0.y, a0.z, a0.w}, {a1.x, a1.y, a1.z, a1.w}};
            float bc[2][4] = {{b0.x, b0.y, b0.z, b0.w}, {b1.x, b1.y, b1.z, b1.w}};
#pragma unroll
            for (int i = 0; i < 2; ++i)
#pragma unroll
              for (int r = 0; r < 4; ++r)
#pragma unroll
                for (int j = 0; j < 2; ++j)
#pragma unroll
                  for (int c = 0; c < 4; ++c)
                      acc[i][j][r][c] += ar[i][r] * bc[j][c];
        }
        __syncthreads();
    }

#pragma unroll
    for (int i = 0; i < 2; ++i)
#pragma unroll
      for (int j = 0; j < 2; ++j)
#pragma unroll
        for (int r = 0; r < 4; ++r) {
            size_t off = (size_t)(bm + i * 64 + ty * 4 + r) * N + bn + j * 64 + tx * 4;
            float4 o;
            o.x = acc[i][j][r][0]; o.y = acc[i][j][r][1];
            o.z = acc[i][j][r][2]; o.w = acc[i][j][r][3];
            if (R) {
                float4 rr = *(const float4*)(R + off);
                o.x += rr.x; o.y += rr.y; o.z += rr.z; o.w += rr.w;
            }
            *(float4*)(C + off) = o;
        }
}

// ---------------------------------------------------------------------------
// Flash attention with Transformer-XL relative position bias.
// Block: (query-block of 32, b, h). 256 threads: tx 0..31 (keys/dims), ty 0..7.
// Thread owns 4 q-rows (ty*4+r) x 2 cols (tx*2+c).
// rel_shift identity: shifted_pos[i][j] = raw_pos[i][j-i+511], valid for j<=i+512.
// ---------------------------------------------------------------------------
__global__ __launch_bounds__(256) void attn_f32(
    const float* __restrict__ kv,   // (TOT*BSZ, 2048): k = [:,0:1024), v = [:,1024:2048)
    const float* __restrict__ qb,   // (SEQ*BSZ, 1024)
    const float* __restrict__ pb,   // (TOT, 1024)   [c][h*64+d]
    const float* __restrict__ u,    // (16,64)
    const float* __restrict__ v,    // (16,64)
    float* __restrict__ awv)        // (SEQ*BSZ, 1024)
{
    const int i0 = blockIdx.x * 32;
    const int b  = blockIdx.y;
    const int h  = blockIdx.z;
    const int t  = threadIdx.x;
    const int tx = t & 31, ty = t >> 5;

    __shared__ float QU[32][68];
    __shared__ float QV[32][68];
    __shared__ float KPV[96][68];   // K tile (64), then P tile (96), then V tile (64)
    __shared__ float Ss[32][68];    // softmaxed probabilities

    // load Q block, add u / v
#pragma unroll
    for (int e = 0; e < 2; ++e) {
        int lin = t + e * 256;                 // 512 float4 = 32 rows x 16
        int row = lin >> 4, c4 = (lin & 15) * 4;
        float4 q4 = *(const float4*)(qb + (size_t)((i0 + row) * BSZ + b) * DIN + h * HD + c4);
        float4 u4 = *(const float4*)(u + h * HD + c4);
        float4 v4 = *(const float4*)(v + h * HD + c4);
        *(float4*)&QU[row][c4] = make_float4(q4.x + u4.x, q4.y + u4.y, q4.z + u4.z, q4.w + u4.w);
        *(float4*)&QV[row][c4] = make_float4(q4.x + v4.x, q4.y + v4.y, q4.z + v4.z, q4.w + v4.w);
    }

    float m[4], l[4], o[4][2];
#pragma unroll
    for (int r = 0; r < 4; ++r) { m[r] = -1e30f; l[r] = 0.f; o[r][0] = 0.f; o[r][1] = 0.f; }

    const int jmax = i0 + 31 + PREV;           // last key any row in this block may see

    for (int j0 = 0; j0 <= jmax && j0 < TOT; j0 += 64) {
        __syncthreads();                        // prev PV done before K overwrites KPV
        // ---- K tile ----
#pragma unroll
        for (int e = 0; e < 4; ++e) {
            int lin = t + e * 256;             // 1024 float4 = 64 rows x 16
            int row = lin >> 4, c4 = (lin & 15) * 4;
            *(float4*)&KPV[row][c4] =
                *(const float4*)(kv + (size_t)((j0 + row) * BSZ + b) * 2048 + h * HD + c4);
        }
        __syncthreads();

        float s[4][2];
#pragma unroll
        for (int r = 0; r < 4; ++r) { s[r][0] = 0.f; s[r][1] = 0.f; }
#pragma unroll
        for (int d4 = 0; d4 < HD; d4 += 4) {
            float4 k0v = *(float4*)&KPV[tx * 2][d4];
            float4 k1v = *(float4*)&KPV[tx * 2 + 1][d4];
#pragma unroll
            for (int r = 0; r < 4; ++r) {
                float4 qu = *(float4*)&QU[ty * 4 + r][d4];
                s[r][0] += qu.x * k0v.x + qu.y * k0v.y + qu.z * k0v.z + qu.w * k0v.w;
                s[r][1] += qu.x * k1v.x + qu.y * k1v.y + qu.z * k1v.z + qu.w * k1v.w;
            }
        }
        __syncthreads();

        // ---- P tile: rows c = cbase..cbase+95, cbase = j0-i0+480 >= 0 ----
        const int cbase = j0 - i0 + 480;
#pragma unroll
        for (int e = 0; e < 6; ++e) {
            int lin = t + e * 256;             // 1536 float4 = 96 rows x 16
            int row = lin >> 4, c4 = (lin & 15) * 4;
            int c = cbase + row;
            float4 pv = (c < TOT) ? *(const float4*)(pb + (size_t)c * DIN + h * HD + c4)
                                  : make_float4(0.f, 0.f, 0.f, 0.f);
            *(float4*)&KPV[row][c4] = pv;
        }
        __syncthreads();

#pragma unroll
        for (int d4 = 0; d4 < HD; d4 += 4) {
            float4 qv[4];
#pragma unroll
            for (int r = 0; r < 4; ++r) qv[r] = *(float4*)&QV[ty * 4 + r][d4];
#pragma unroll
            for (int r = 0; r < 4; ++r)
#pragma unroll
                for (int c = 0; c < 2; ++c) {
                    int pr = (tx * 2 + c) - (ty * 4 + r) + 31;   // in [0,94]
                    float4 pp = *(float4*)&KPV[pr][d4];
                    s[r][c] += qv[r].x * pp.x + qv[r].y * pp.y + qv[r].z * pp.z + qv[r].w * pp.w;
                }
        }

        // ---- scale + causal/memory mask ----
#pragma unroll
        for (int r = 0; r < 4; ++r)
#pragma unroll
            for (int c = 0; c < 2; ++c) {
                int i = i0 + ty * 4 + r, j = j0 + tx * 2 + c;
                s[r][c] = (j > i + PREV) ? -1e30f : s[r][c] * 0.125f;
            }

        // ---- online softmax (row reduce across 32 tx lanes = half-wave) ----
#pragma unroll
        for (int r = 0; r < 4; ++r) {
            float tm = fmaxf(s[r][0], s[r][1]);
#pragma unroll
            for (int w = 1; w < 32; w <<= 1) tm = fmaxf(tm, __shfl_xor(tm, w));
            float nm = fmaxf(m[r], tm);
            float f  = __expf(m[r] - nm);
            float p0 = __expf(s[r][0] - nm);
            float p1 = __expf(s[r][1] - nm);
            float ts = p0 + p1;
#pragma unroll
            for (int w = 1; w < 32; w <<= 1) ts += __shfl_xor(ts, w);
            l[r] = l[r] * f + ts;
            o[r][0] *= f; o[r][1] *= f;
            m[r] = nm;
            s[r][0] = p0; s[r][1] = p1;
        }

        // ---- stash P(probabilities), load V, PV ----
#pragma unroll
        for (int r = 0; r < 4; ++r) {
            Ss[ty * 4 + r][tx * 2]     = s[r][0];
            Ss[ty * 4 + r][tx * 2 + 1] = s[r][1];
        }
        __syncthreads();                        // P-tile reads + Ss writes done
#pragma unroll
        for (int e = 0; e < 4; ++e) {
            int lin = t + e * 256;
            int row = lin >> 4, c4 = (lin & 15) * 4;
            *(float4*)&KPV[row][c4] =
                *(const float4*)(kv + (size_t)((j0 + row) * BSZ + b) * 2048 + 1024 + h * HD + c4);
        }
        __syncthreads();

#pragma unroll
        for (int j = 0; j < 64; j += 4) {
            float pj[4][4];
#pragma unroll
            for (int r = 0; r < 4; ++r) {
                float4 p4 = *(float4*)&Ss[ty * 4 + r][j];
                pj[r][0] = p4.x; pj[r][1] = p4.y; pj[r][2] = p4.z; pj[r][3] = p4.w;
            }
#pragma unroll
            for (int jj = 0; jj < 4; ++jj) {
                float vv0 = KPV[j + jj][tx * 2];
                float vv1 = KPV[j + jj][tx * 2 + 1];
#pragma unroll
                for (int r = 0; r < 4; ++r) {
                    o[r][0] += pj[r][jj] * vv0;
                    o[r][1] += pj[r][jj] * vv1;
                }
            }
        }
    }

#pragma unroll
    for (int r = 0; r < 4; ++r) {
        float inv = 1.f / l[r];
        size_t off = (size_t)((i0 + ty * 4 + r) * BSZ + b) * DIN + h * HD + tx * 2;
        float2 ov = make_float2(o[r][0] * inv, o[r][1] * inv);
        *(float2*)(awv + off) = ov;
    }
}

// ---------------------------------------------------------------------------
// In-place LayerNorm over last dim (1024). One block per row.
// ---------------------------------------------------------------------------
__global__ __launch_bounds__(256) void ln_f32(
    float* __restrict__ out, const float* __restrict__ gamma, const float* __restrict__ beta)
{
    const int row = blockIdx.x;
    const int t = threadIdx.x;
    float4 x = *(float4*)(out + (size_t)row * DIN + t * 4);
    float s  = x.x + x.y + x.z + x.w;
    float ss = x.x * x.x + x.y * x.y + x.z * x.z + x.w * x.w;
#pragma unroll
    for (int w = 1; w < 64; w <<= 1) { s += __shfl_xor(s, w); ss += __shfl_xor(ss, w); }
    __shared__ float sbuf[4], ssbuf[4];
    const int wave = t >> 6, lane = t & 63;
    if (lane == 0) { sbuf[wave] = s; ssbuf[wave] = ss; }
    __syncthreads();
    s  = sbuf[0] + sbuf[1] + sbuf[2] + sbuf[3];
    ss = ssbuf[0] + ssbuf[1] + ssbuf[2] + ssbuf[3];
    const float mu   = s * (1.f / DIN);
    const float var  = ss * (1.f / DIN) - mu * mu;
    const float rstd = rsqrtf(var + 1e-5f);
    float4 g  = *(const float4*)(gamma + t * 4);
    float4 bb = *(const float4*)(beta + t * 4);
    float4 y;
    y.x = (x.x - mu) * rstd * g.x + bb.x;
    y.y = (x.y - mu) * rstd * g.y + bb.y;
    y.z = (x.z - mu) * rstd * g.z + bb.z;
    y.w = (x.w - mu) * rstd * g.w + bb.w;
    *(float4*)(out + (size_t)row * DIN + t * 4) = y;
}

// ---------------------------------------------------------------------------
extern "C" void kernel_launch(void* const* d_in, const int* in_sizes, int n_in,
                              void* d_out, int out_size, void* d_ws, size_t ws_size,
                              hipStream_t stream)
{
    const float* input_ = (const float*)d_in[0];
    const float* pos    = (const float*)d_in[1];
    const float* memory = (const float*)d_in[2];
    const float* u      = (const float*)d_in[3];
    const float* v      = (const float*)d_in[4];
    // d_in[5] = mask (bool) — computed analytically in-kernel: j > i + PREV
    const float* W_kv   = (const float*)d_in[6];
    const float* W_q    = (const float*)d_in[7];
    const float* W_p    = (const float*)d_in[8];
    const float* W_out  = (const float*)d_in[9];
    const float* gamma  = (const float*)d_in[10];
    const float* beta   = (const float*)d_in[11];

    float* ws  = (float*)d_ws;                 // needs 100 MB of workspace
    float* kv  = ws;                                         // 8192 x 2048
    float* qbf = kv  + (size_t)TOT * BSZ * 2048;             // 4096 x 1024
    float* pbf = qbf + (size_t)SEQ * BSZ * DIN;              // 1024 x 1024
    float* awv = pbf + (size_t)TOT * DIN;                    // 4096 x 1024
    float* outf = (float*)d_out;

    // projections
    gemm_f32<<<dim3(16, 32), 256, 0, stream>>>(memory, W_kv, nullptr, kv, 4096, 2048, 1024);
    gemm_f32<<<dim3(16, 32), 256, 0, stream>>>(input_, W_kv, nullptr, kv + (size_t)4096 * 2048, 4096, 2048, 1024);
    gemm_f32<<<dim3(8, 32), 256, 0, stream>>>(input_, W_q, nullptr, qbf, 4096, 1024, 1024);
    gemm_f32<<<dim3(8, 8), 256, 0, stream>>>(pos, W_p, nullptr, pbf, 1024, 1024, 1024);
    // fused attention
    attn_f32<<<dim3(SEQ / 32, BSZ, NH), 256, 0, stream>>>(kv, qbf, pbf, u, v, awv);
    // out projection + residual, then in-place LayerNorm
    gemm_f32<<<dim3(8, 32), 256, 0, stream>>>(awv, W_out, input_, outf, 4096, 1024, 1024);
    ln_f32<<<SEQ * BSZ, 256, 0, stream>>>(outf, gamma, beta);
}

// Round 2
// 232.014 us; speedup vs baseline: 51.4865x; 51.4865x over previous
//
#include <hip/hip_runtime.h>
#include <math.h>

#define SEQ  512
#define PREV 512
#define TOT  1024
#define BSZ  8
#define DIN  1024
#define NH   16
#define HD   64

typedef __bf16 bf16;
typedef __bf16 bf16x8 __attribute__((ext_vector_type(8)));
typedef float  f32x4  __attribute__((ext_vector_type(4)));

__device__ __forceinline__ f32x4 MFMA16(bf16x8 a, bf16x8 b, f32x4 c) {
    return __builtin_amdgcn_mfma_f32_16x16x32_bf16(a, b, c, 0, 0, 0);
}

#define GLOAD16(g, l) __builtin_amdgcn_global_load_lds( \
    (const __attribute__((address_space(1))) void*)(g), \
    (__attribute__((address_space(3))) void*)(l), 16, 0, 0)

__device__ __forceinline__ unsigned short bfbits(float x) {
    return __builtin_bit_cast(unsigned short, (bf16)x);
}

// ---------------------------------------------------------------------------
// cast f32 -> bf16, two concatenated sources (A then B). ntot mult of 1024.
// ---------------------------------------------------------------------------
__global__ __launch_bounds__(256) void cast_cat(
    const float* __restrict__ A, int nA, const float* __restrict__ B,
    bf16* __restrict__ out)
{
    int e4 = (blockIdx.x * 256 + threadIdx.x) * 4;
    float4 x = (e4 < nA) ? *(const float4*)(A + e4) : *(const float4*)(B + e4 - nA);
    union { bf16 h[4]; ushort4 u4; } pk;
    pk.h[0] = (bf16)x.x; pk.h[1] = (bf16)x.y; pk.h[2] = (bf16)x.z; pk.h[3] = (bf16)x.w;
    *(ushort4*)(out + e4) = pk.u4;
}

// ---------------------------------------------------------------------------
// transpose + cast: Wt[n][k] (bf16) = W[k][n] (f32). 32x32 tiles.
// ---------------------------------------------------------------------------
__global__ __launch_bounds__(256) void transcast(
    const float* __restrict__ W, bf16* __restrict__ Wt, int K, int N)
{
    __shared__ float tile[32][33];
    const int t = threadIdx.x;
    const int bk = blockIdx.y * 32, bn = blockIdx.x * 32;
    const int r = t >> 3, c4 = (t & 7) * 4;
    float4 x = *(const float4*)(W + (size_t)(bk + r) * N + bn + c4);
    tile[r][c4 + 0] = x.x; tile[r][c4 + 1] = x.y;
    tile[r][c4 + 2] = x.z; tile[r][c4 + 3] = x.w;
    __syncthreads();
    union { bf16 h[4]; ushort4 u4; } pk;
#pragma unroll
    for (int i = 0; i < 4; ++i) pk.h[i] = (bf16)tile[c4 + i][r];
    *(ushort4*)(Wt + (size_t)(bn + r) * K + bk + c4) = pk.u4;
}

// ---------------------------------------------------------------------------
// bf16 MFMA GEMM: C[M][N] = A[M][K] @ B^T  (B passed as Bt[N][K], both bf16).
// 128x128 tile, BK=64, 4 waves (2x2), 16x16x32 MFMA, global_load_lds staging
// with XOR-(row&7) pre-swizzled source; swizzled ds_read_b128 frag reads.
// FOUT=0: bf16 out. FOUT=1: f32 out = acc + Rres.
// ---------------------------------------------------------------------------
template<int FOUT>
__global__ __launch_bounds__(256) void gemm_mfma(
    const bf16* __restrict__ A, const bf16* __restrict__ Bt,
    const float* __restrict__ Rres, bf16* __restrict__ Cb,
    float* __restrict__ Cf, int M, int N, int K)
{
    __shared__ __align__(16) bf16 A_s[128 * 64];
    __shared__ __align__(16) bf16 B_s[128 * 64];
    const int t = threadIdx.x;
    const int w = t >> 6, lane = t & 63;
    const int li = lane & 15, hi = lane >> 4;
    const int wr = w >> 1, wc = w & 1;
    const int bm = blockIdx.y * 128, bn = blockIdx.x * 128;
    const int l3 = lane >> 3, l7 = lane & 7;
    const int srcoct = ((l7 ^ l3) * 8);

    f32x4 acc[4][4];
#pragma unroll
    for (int m = 0; m < 4; ++m)
#pragma unroll
        for (int n = 0; n < 4; ++n) acc[m][n] = (f32x4){0.f, 0.f, 0.f, 0.f};

    auto stage = [&](int k0) {
#pragma unroll
        for (int i = 0; i < 4; ++i) {
            int c = w * 4 + i;
            const bf16* ga = A + (size_t)(bm + c * 8 + l3) * K + k0 + srcoct;
            GLOAD16(ga, &A_s[c * 512]);
            const bf16* gb = Bt + (size_t)(bn + c * 8 + l3) * K + k0 + srcoct;
            GLOAD16(gb, &B_s[c * 512]);
        }
    };

    stage(0);
    const int nk = K >> 6;
    for (int ks = 0; ks < nk; ++ks) {
        __syncthreads();
#pragma unroll
        for (int kk = 0; kk < 2; ++kk) {
            bf16x8 af[4], bfr[4];
#pragma unroll
            for (int m = 0; m < 4; ++m) {
                int row = wr * 64 + m * 16 + li;
                af[m] = *(const bf16x8*)&A_s[row * 64 + ((kk * 32 + hi * 8) ^ ((row & 7) * 8))];
            }
#pragma unroll
            for (int n = 0; n < 4; ++n) {
                int row = wc * 64 + n * 16 + li;
                bfr[n] = *(const bf16x8*)&B_s[row * 64 + ((kk * 32 + hi * 8) ^ ((row & 7) * 8))];
            }
#pragma unroll
            for (int m = 0; m < 4; ++m)
#pragma unroll
                for (int n = 0; n < 4; ++n)
                    acc[m][n] = MFMA16(af[m], bfr[n], acc[m][n]);
        }
        __syncthreads();
        if (ks + 1 < nk) stage((ks + 1) << 6);
    }

#pragma unroll
    for (int m = 0; m < 4; ++m)
#pragma unroll
        for (int n = 0; n < 4; ++n)
#pragma unroll
            for (int r = 0; r < 4; ++r) {
                int row = bm + wr * 64 + m * 16 + hi * 4 + r;
                int col = bn + wc * 64 + n * 16 + li;
                size_t off = (size_t)row * N + col;
                if (FOUT) Cf[off] = acc[m][n][r] + Rres[off];
                else      Cb[off] = (bf16)acc[m][n][r];
            }
}

// ---------------------------------------------------------------------------
// Fused flash attention (Transformer-XL rel-pos), bf16 MFMA 16x16x32.
// Block = (q-block of 64, b, h), 4 waves; wave owns 16 q-rows.
// Swapped QK^T: S^T = K.QU^T so lane (li=lane&15) owns one q-row.
// rel_shift: pos score for (i,j) = QV_i . P[j-i+511]; banded raw GEMM R^T
// into wave-private LDS scratch, shifted read cl = lj+15-li.
// V staged transposed with j-rotation by (d>>3) to kill transpose-write
// bank conflicts.
// ---------------------------------------------------------------------------
__global__ __launch_bounds__(256) void attn_mfma(
    const bf16* __restrict__ kv, const bf16* __restrict__ qb,
    const bf16* __restrict__ pb, const float* __restrict__ u,
    const float* __restrict__ v, bf16* __restrict__ awv)
{
    const int i0 = blockIdx.x * 64;
    const int b  = blockIdx.y;
    const int h  = blockIdx.z;
    const int t  = threadIdx.x;
    const int w  = t >> 6;
    const int lane = t & 63;
    const int li = lane & 15, hi = lane >> 4;

    __shared__ __align__(16) bf16 K_s[64][72];
    __shared__ __align__(16) bf16 V_s[64][72];   // V^T with j-rotation by (d>>3)
    __shared__ __align__(16) bf16 P_s[128][72];
    __shared__ __align__(16) char SCR[4][5760];  // per-wave: R^T [80][18] f32 / Ps [16][72] bf16

    float* rsc = (float*)SCR[w];
    bf16*  ps  = (bf16*)SCR[w];

    // Q fragments (+u content / +v position), bf16
    bf16x8 qu[2], qv[2];
    {
        const int qrow = (i0 + w * 16 + li) * BSZ + b;
#pragma unroll
        for (int kk = 0; kk < 2; ++kk) {
            bf16x8 q8 = *(const bf16x8*)(qb + (size_t)qrow * DIN + h * HD + kk * 32 + hi * 8);
            const float* up = u + h * HD + kk * 32 + hi * 8;
            const float* vp = v + h * HD + kk * 32 + hi * 8;
#pragma unroll
            for (int m = 0; m < 8; ++m) {
                float qf = (float)q8[m];
                qu[kk][m] = (bf16)(qf + up[m]);
                qv[kk][m] = (bf16)(qf + vp[m]);
            }
        }
    }

    float mrun = -1e30f, lrun = 0.f;
    f32x4 o[4];
#pragma unroll
    for (int dt = 0; dt < 4; ++dt) o[dt] = (f32x4){0.f, 0.f, 0.f, 0.f};

    const int nt = blockIdx.x + 9;          // tiles of 64 keys, last = i0+512
    const int basew = 48 - w * 16;          // wave's band base in P_s

    bf16x8 kreg[2], vreg[2], preg[4];

    auto load_tile = [&](int t0) {
        const int j0 = t0 * 64;
#pragma unroll
        for (int e = 0; e < 2; ++e) {
            int lin = t + e * 256;
            int jr = lin >> 3, c8 = (lin & 7) * 8;
            const bf16* base = kv + (size_t)((j0 + jr) * BSZ + b) * 2048 + h * HD + c8;
            kreg[e] = *(const bf16x8*)base;
            vreg[e] = *(const bf16x8*)(base + 1024);
        }
        const int pbase = j0 - i0 + 448;
#pragma unroll
        for (int e = 0; e < 4; ++e) {
            int lin = t + e * 256;
            int pr = lin >> 3, c8 = (lin & 7) * 8;
            int c = pbase + pr;
            if (c < TOT) preg[e] = *(const bf16x8*)(pb + (size_t)c * DIN + h * HD + c8);
            else {
#pragma unroll
                for (int m = 0; m < 8; ++m) preg[e][m] = (bf16)0.f;
            }
        }
    };

    auto store_tile = [&]() {
#pragma unroll
        for (int e = 0; e < 2; ++e) {
            int lin = t + e * 256;
            int jr = lin >> 3, c8 = (lin & 7) * 8;
            *(bf16x8*)&K_s[jr][c8] = kreg[e];
            int jrot = (jr + (lin & 7) * 8) & 63;   // rotate j by 8*(d>>3), d0=8*(lin&7)
#pragma unroll
            for (int mm = 0; mm < 8; ++mm) V_s[c8 + mm][jrot] = vreg[e][mm];
        }
#pragma unroll
        for (int e = 0; e < 4; ++e) {
            int lin = t + e * 256;
            int pr = lin >> 3, c8 = (lin & 7) * 8;
            *(bf16x8*)&P_s[pr][c8] = preg[e];
        }
    };

    load_tile(0);
    for (int t0 = 0; t0 < nt; ++t0) {
        const int j0 = t0 * 64;
        __syncthreads();                 // previous tile's LDS reads done
        store_tile();
        __syncthreads();                 // staged data visible
        if (t0 + 1 < nt) load_tile(t0 + 1);   // prefetch overlaps compute

        // ---- content scores S^T = K . QU^T ----
        f32x4 st[4];
#pragma unroll
        for (int ct = 0; ct < 4; ++ct) {
            f32x4 a = (f32x4){0.f, 0.f, 0.f, 0.f};
#pragma unroll
            for (int kk = 0; kk < 2; ++kk) {
                bf16x8 kf = *(const bf16x8*)&K_s[ct * 16 + li][kk * 32 + hi * 8];
                a = MFMA16(kf, qu[kk], a);
            }
            st[ct] = a;
        }

        // ---- raw position scores R^T = P_band . QV^T -> wave scratch ----
#pragma unroll
        for (int pt = 0; pt < 5; ++pt) {
            f32x4 a = (f32x4){0.f, 0.f, 0.f, 0.f};
#pragma unroll
            for (int kk = 0; kk < 2; ++kk) {
                bf16x8 pf = *(const bf16x8*)&P_s[basew + pt * 16 + li][kk * 32 + hi * 8];
                a = MFMA16(pf, qv[kk], a);
            }
#pragma unroll
            for (int r = 0; r < 4; ++r) rsc[(pt * 16 + hi * 4 + r) * 18 + li] = a[r];
        }

        // ---- assemble S (shifted pos add), scale, mask ----
        float pr_[4][4];
        float rowmax = -1e30f;
#pragma unroll
        for (int ct = 0; ct < 4; ++ct)
#pragma unroll
            for (int r = 0; r < 4; ++r) {
                int lj = ct * 16 + hi * 4 + r;
                float sv = st[ct][r] + rsc[(lj + 15 - li) * 18 + li];
                sv *= 0.125f;
                if (j0 + lj > i0 + w * 16 + li + PREV) sv = -1e30f;
                pr_[ct][r] = sv;
                rowmax = fmaxf(rowmax, sv);
            }
        rowmax = fmaxf(rowmax, __shfl_xor(rowmax, 16));
        rowmax = fmaxf(rowmax, __shfl_xor(rowmax, 32));

        float newm = fmaxf(mrun, rowmax);
        float fsc = __expf(mrun - newm);
        float rowsum = 0.f;
#pragma unroll
        for (int ct = 0; ct < 4; ++ct)
#pragma unroll
            for (int r = 0; r < 4; ++r) {
                float p = __expf(pr_[ct][r] - newm);
                pr_[ct][r] = p;
                rowsum += p;
            }
        rowsum += __shfl_xor(rowsum, 16);
        rowsum += __shfl_xor(rowsum, 32);
        lrun = lrun * fsc + rowsum;
        mrun = newm;

        // rescale O (output rows are hi*4+r -> redistribute factors)
        float fr[4];
#pragma unroll
        for (int r = 0; r < 4; ++r) fr[r] = __shfl(fsc, hi * 4 + r);
#pragma unroll
        for (int dt = 0; dt < 4; ++dt)
#pragma unroll
            for (int r = 0; r < 4; ++r) o[dt][r] *= fr[r];

        // ---- write probabilities bf16 to wave scratch (overlays R^T) ----
#pragma unroll
        for (int ct = 0; ct < 4; ++ct)
#pragma unroll
            for (int rr = 0; rr < 2; ++rr) {
                unsigned int pw = (unsigned int)bfbits(pr_[ct][2 * rr]) |
                                  ((unsigned int)bfbits(pr_[ct][2 * rr + 1]) << 16);
                *(unsigned int*)&ps[li * 72 + ct * 16 + hi * 4 + 2 * rr] = pw;
            }

        // ---- PV: O += P . V ----
#pragma unroll
        for (int kk = 0; kk < 2; ++kk) {
            bf16x8 pa = *(const bf16x8*)&ps[li * 72 + kk * 32 + hi * 8];
#pragma unroll
            for (int dt = 0; dt < 4; ++dt) {
                int d = dt * 16 + li;
                bf16x8 vf = *(const bf16x8*)&V_s[d][(kk * 32 + hi * 8 + (d >> 3) * 8) & 63];
                o[dt] = MFMA16(pa, vf, o[dt]);
            }
        }
    }

    // ---- epilogue: normalize and store ----
    float lr[4];
#pragma unroll
    for (int r = 0; r < 4; ++r) lr[r] = __shfl(lrun, hi * 4 + r);
#pragma unroll
    for (int dt = 0; dt < 4; ++dt)
#pragma unroll
        for (int r = 0; r < 4; ++r) {
            int row = i0 + w * 16 + hi * 4 + r;
            awv[(size_t)(row * BSZ + b) * DIN + h * HD + dt * 16 + li] = (bf16)(o[dt][r] / lr[r]);
        }
}

// ---------------------------------------------------------------------------
// In-place LayerNorm over last dim (1024). One block per row.
// ---------------------------------------------------------------------------
__global__ __launch_bounds__(256) void ln_f32(
    float* __restrict__ out, const float* __restrict__ gamma, const float* __restrict__ beta)
{
    const int row = blockIdx.x;
    const int t = threadIdx.x;
    float4 x = *(float4*)(out + (size_t)row * DIN + t * 4);
    float s  = x.x + x.y + x.z + x.w;
    float ss = x.x * x.x + x.y * x.y + x.z * x.z + x.w * x.w;
#pragma unroll
    for (int wd = 1; wd < 64; wd <<= 1) { s += __shfl_xor(s, wd); ss += __shfl_xor(ss, wd); }
    __shared__ float sbuf[4], ssbuf[4];
    const int wave = t >> 6, lanei = t & 63;
    if (lanei == 0) { sbuf[wave] = s; ssbuf[wave] = ss; }
    __syncthreads();
    s  = sbuf[0] + sbuf[1] + sbuf[2] + sbuf[3];
    ss = ssbuf[0] + ssbuf[1] + ssbuf[2] + ssbuf[3];
    const float mu   = s * (1.f / DIN);
    const float var  = ss * (1.f / DIN) - mu * mu;
    const float rstd = rsqrtf(var + 1e-5f);
    float4 g  = *(const float4*)(gamma + t * 4);
    float4 bb = *(const float4*)(beta + t * 4);
    float4 y;
    y.x = (x.x - mu) * rstd * g.x + bb.x;
    y.y = (x.y - mu) * rstd * g.y + bb.y;
    y.z = (x.z - mu) * rstd * g.z + bb.z;
    y.w = (x.w - mu) * rstd * g.w + bb.w;
    *(float4*)(out + (size_t)row * DIN + t * 4) = y;
}

// ---------------------------------------------------------------------------
extern "C" void kernel_launch(void* const* d_in, const int* in_sizes, int n_in,
                              void* d_out, int out_size, void* d_ws, size_t ws_size,
                              hipStream_t stream)
{
    const float* input_ = (const float*)d_in[0];
    const float* pos    = (const float*)d_in[1];
    const float* memory = (const float*)d_in[2];
    const float* u      = (const float*)d_in[3];
    const float* v      = (const float*)d_in[4];
    // d_in[5] = mask: computed analytically (j > i + PREV)
    const float* W_kv   = (const float*)d_in[6];
    const float* W_q    = (const float*)d_in[7];
    const float* W_p    = (const float*)d_in[8];
    const float* W_out  = (const float*)d_in[9];
    const float* gamma  = (const float*)d_in[10];
    const float* beta   = (const float*)d_in[11];

    bf16* iwm  = (bf16*)d_ws;                      // [8192][1024]  (memory ; input)
    bf16* kvb  = iwm  + (size_t)8192 * 1024;       // [8192][2048]  k | v
    bf16* qbf  = kvb  + (size_t)8192 * 2048;       // [4096][1024]
    bf16* pbf  = qbf  + (size_t)4096 * 1024;       // [1024][1024]
    bf16* posb = pbf  + (size_t)1024 * 1024;       // [1024][1024]
    bf16* wkv  = posb + (size_t)1024 * 1024;       // [2048][1024]  W_kv^T
    bf16* wq   = wkv  + (size_t)2048 * 1024;       // [1024][1024]
    bf16* wp   = wq   + (size_t)1024 * 1024;
    bf16* wo   = wp   + (size_t)1024 * 1024;
    bf16* awvb = wo   + (size_t)1024 * 1024;       // [4096][1024]
    float* outf = (float*)d_out;

    // casts / transposes
    cast_cat<<<8192, 256, 0, stream>>>(memory, 4194304, input_, iwm);
    cast_cat<<<1024, 256, 0, stream>>>(pos, 1048576, pos, posb);
    transcast<<<dim3(64, 32), 256, 0, stream>>>(W_kv,  wkv, 1024, 2048);
    transcast<<<dim3(32, 32), 256, 0, stream>>>(W_q,   wq,  1024, 1024);
    transcast<<<dim3(32, 32), 256, 0, stream>>>(W_p,   wp,  1024, 1024);
    transcast<<<dim3(32, 32), 256, 0, stream>>>(W_out, wo,  1024, 1024);

    // projections (bf16 out)
    gemm_mfma<0><<<dim3(16, 64), 256, 0, stream>>>(iwm, wkv, nullptr, kvb, nullptr, 8192, 2048, 1024);
    gemm_mfma<0><<<dim3(8, 32), 256, 0, stream>>>(iwm + (size_t)4096 * 1024, wq, nullptr, qbf, nullptr, 4096, 1024, 1024);
    gemm_mfma<0><<<dim3(8, 8),  256, 0, stream>>>(posb, wp, nullptr, pbf, nullptr, 1024, 1024, 1024);

    // fused attention
    attn_mfma<<<dim3(8, 8, 16), 256, 0, stream>>>(kvb, qbf, pbf, u, v, awvb);

    // out projection + residual (f32), then LayerNorm
    gemm_mfma<1><<<dim3(8, 32), 256, 0, stream>>>(awvb, wo, input_, nullptr, outf, 4096, 1024, 1024);
    ln_f32<<<4096, 256, 0, stream>>>(outf, gamma, beta);
}

// Round 3
// 229.742 us; speedup vs baseline: 51.9956x; 1.0099x over previous
//
#include <hip/hip_runtime.h>
#include <math.h>

#define SEQ  512
#define PREV 512
#define TOT  1024
#define BSZ  8
#define DIN  1024
#define NH   16
#define HD   64

typedef __bf16 bf16;
typedef __bf16 bf16x8 __attribute__((ext_vector_type(8)));
typedef float  f32x4  __attribute__((ext_vector_type(4)));

__device__ __forceinline__ f32x4 MFMA16(bf16x8 a, bf16x8 b, f32x4 c) {
    return __builtin_amdgcn_mfma_f32_16x16x32_bf16(a, b, c, 0, 0, 0);
}

#define GLOAD16(g, l) __builtin_amdgcn_global_load_lds( \
    (const __attribute__((address_space(1))) void*)(g), \
    (__attribute__((address_space(3))) void*)(l), 16, 0, 0)

__device__ __forceinline__ unsigned short bfbits(float x) {
    return __builtin_bit_cast(unsigned short, (bf16)x);
}

// ---------------------------------------------------------------------------
// cast f32 -> bf16, two concatenated sources (A then B).
// ---------------------------------------------------------------------------
__global__ __launch_bounds__(256) void cast_cat(
    const float* __restrict__ A, int nA, const float* __restrict__ B,
    bf16* __restrict__ out)
{
    int e4 = (blockIdx.x * 256 + threadIdx.x) * 4;
    float4 x = (e4 < nA) ? *(const float4*)(A + e4) : *(const float4*)(B + e4 - nA);
    union { bf16 h[4]; ushort4 u4; } pk;
    pk.h[0] = (bf16)x.x; pk.h[1] = (bf16)x.y; pk.h[2] = (bf16)x.z; pk.h[3] = (bf16)x.w;
    *(ushort4*)(out + e4) = pk.u4;
}

// ---------------------------------------------------------------------------
// merged transpose+cast for all 4 weights: Wt[n][k] = W[k][n]. K=1024.
// grid.x: [0,64) W_kv | [64,96) W_q | [96,128) W_p | [128,160) W_out
// ---------------------------------------------------------------------------
__global__ __launch_bounds__(256) void transcast_all(
    const float* __restrict__ W_kv, const float* __restrict__ W_q,
    const float* __restrict__ W_p,  const float* __restrict__ W_out,
    bf16* __restrict__ wkv, bf16* __restrict__ wq,
    bf16* __restrict__ wp,  bf16* __restrict__ wo)
{
    __shared__ float tile[32][33];
    const int bx = blockIdx.x;
    const float* W; bf16* Wt; int N, bn;
    if (bx < 64)       { W = W_kv;  Wt = wkv; N = 2048; bn = bx * 32; }
    else if (bx < 96)  { W = W_q;   Wt = wq;  N = 1024; bn = (bx - 64) * 32; }
    else if (bx < 128) { W = W_p;   Wt = wp;  N = 1024; bn = (bx - 96) * 32; }
    else               { W = W_out; Wt = wo;  N = 1024; bn = (bx - 128) * 32; }
    const int t = threadIdx.x;
    const int bk = blockIdx.y * 32;
    const int r = t >> 3, c4 = (t & 7) * 4;
    float4 x = *(const float4*)(W + (size_t)(bk + r) * N + bn + c4);
    tile[r][c4 + 0] = x.x; tile[r][c4 + 1] = x.y;
    tile[r][c4 + 2] = x.z; tile[r][c4 + 3] = x.w;
    __syncthreads();
    union { bf16 h[4]; ushort4 u4; } pk;
#pragma unroll
    for (int i = 0; i < 4; ++i) pk.h[i] = (bf16)tile[c4 + i][r];
    *(ushort4*)(Wt + (size_t)(bn + r) * 1024 + bk + c4) = pk.u4;
}

// ---------------------------------------------------------------------------
// bf16 MFMA GEMM: C[M][N] = A[M][K] @ B^T  (B passed as Bt[N][K], both bf16).
// 128x128 tile, BK=64, 4 waves (2x2), 16x16x32 MFMA, global_load_lds staging
// with XOR-(row&7) pre-swizzled source; swizzled ds_read_b128 frag reads.
// FOUT=0: bf16 out. FOUT=1: f32 out = acc + Rres.
// ---------------------------------------------------------------------------
template<int FOUT>
__global__ __launch_bounds__(256) void gemm_mfma(
    const bf16* __restrict__ A, const bf16* __restrict__ Bt,
    const float* __restrict__ Rres, bf16* __restrict__ Cb,
    float* __restrict__ Cf, int M, int N, int K)
{
    __shared__ __align__(16) bf16 A_s[128 * 64];
    __shared__ __align__(16) bf16 B_s[128 * 64];
    const int t = threadIdx.x;
    const int w = t >> 6, lane = t & 63;
    const int li = lane & 15, hi = lane >> 4;
    const int wr = w >> 1, wc = w & 1;
    const int bm = blockIdx.y * 128, bn = blockIdx.x * 128;
    const int l3 = lane >> 3, l7 = lane & 7;
    const int srcoct = ((l7 ^ l3) * 8);

    f32x4 acc[4][4];
#pragma unroll
    for (int m = 0; m < 4; ++m)
#pragma unroll
        for (int n = 0; n < 4; ++n) acc[m][n] = (f32x4){0.f, 0.f, 0.f, 0.f};

    auto stage = [&](int k0) {
#pragma unroll
        for (int i = 0; i < 4; ++i) {
            int c = w * 4 + i;
            const bf16* ga = A + (size_t)(bm + c * 8 + l3) * K + k0 + srcoct;
            GLOAD16(ga, &A_s[c * 512]);
            const bf16* gb = Bt + (size_t)(bn + c * 8 + l3) * K + k0 + srcoct;
            GLOAD16(gb, &B_s[c * 512]);
        }
    };

    stage(0);
    const int nk = K >> 6;
    for (int ks = 0; ks < nk; ++ks) {
        __syncthreads();
#pragma unroll
        for (int kk = 0; kk < 2; ++kk) {
            bf16x8 af[4], bfr[4];
#pragma unroll
            for (int m = 0; m < 4; ++m) {
                int row = wr * 64 + m * 16 + li;
                af[m] = *(const bf16x8*)&A_s[row * 64 + ((kk * 32 + hi * 8) ^ ((row & 7) * 8))];
            }
#pragma unroll
            for (int n = 0; n < 4; ++n) {
                int row = wc * 64 + n * 16 + li;
                bfr[n] = *(const bf16x8*)&B_s[row * 64 + ((kk * 32 + hi * 8) ^ ((row & 7) * 8))];
            }
#pragma unroll
            for (int m = 0; m < 4; ++m)
#pragma unroll
                for (int n = 0; n < 4; ++n)
                    acc[m][n] = MFMA16(af[m], bfr[n], acc[m][n]);
        }
        __syncthreads();
        if (ks + 1 < nk) stage((ks + 1) << 6);
    }

#pragma unroll
    for (int m = 0; m < 4; ++m)
#pragma unroll
        for (int n = 0; n < 4; ++n)
#pragma unroll
            for (int r = 0; r < 4; ++r) {
                int row = bm + wr * 64 + m * 16 + hi * 4 + r;
                int col = bn + wc * 64 + n * 16 + li;
                size_t off = (size_t)row * N + col;
                if (FOUT) Cf[off] = acc[m][n][r] + Rres[off];
                else      Cb[off] = (bf16)acc[m][n][r];
            }
}

// ---------------------------------------------------------------------------
// Fused flash attention (Transformer-XL rel-pos), bf16 MFMA 16x16x32.
// Block = (q-block of 64, b, h), 4 waves; wave owns 16 q-rows.
// Swapped QK^T: S^T = K.QU^T so lane (li=lane&15) owns one q-row.
// rel_shift: pos score for (i,j) = QV_i . P[j-i+511]; banded raw GEMM R^T
// into wave-private bf16 LDS scratch, shifted read row = lj+15-li.
// Defer-max (T13): skip O-rescale while __all(rowmax - m <= 8).
// LDS 48384 B -> 3 blocks/CU.
// ---------------------------------------------------------------------------
__global__ __launch_bounds__(256) void attn_mfma(
    const bf16* __restrict__ kv, const bf16* __restrict__ qb,
    const bf16* __restrict__ pb, const float* __restrict__ u,
    const float* __restrict__ v, bf16* __restrict__ awv)
{
    const int i0 = blockIdx.x * 64;
    const int b  = blockIdx.y;
    const int h  = blockIdx.z;
    const int t  = threadIdx.x;
    const int w  = t >> 6;
    const int lane = t & 63;
    const int li = lane & 15, hi = lane >> 4;

    __shared__ __align__(16) bf16 K_s[64][72];
    __shared__ __align__(16) bf16 V_s[64][72];   // V^T with j-rotation by (d>>3)
    __shared__ __align__(16) bf16 P_s[128][72];
    __shared__ __align__(16) char SCR[4][2880];  // per-wave: R^T [80][18] bf16 / Ps [16][72] bf16

    bf16* rsc = (bf16*)SCR[w];
    bf16* ps  = (bf16*)SCR[w];

    // Q fragments (+u content / +v position), bf16
    bf16x8 qu[2], qv[2];
    {
        const int qrow = (i0 + w * 16 + li) * BSZ + b;
#pragma unroll
        for (int kk = 0; kk < 2; ++kk) {
            bf16x8 q8 = *(const bf16x8*)(qb + (size_t)qrow * DIN + h * HD + kk * 32 + hi * 8);
            const float* up = u + h * HD + kk * 32 + hi * 8;
            const float* vp = v + h * HD + kk * 32 + hi * 8;
#pragma unroll
            for (int m = 0; m < 8; ++m) {
                float qf = (float)q8[m];
                qu[kk][m] = (bf16)(qf + up[m]);
                qv[kk][m] = (bf16)(qf + vp[m]);
            }
        }
    }

    float mrun = -1e30f, lrun = 0.f;
    f32x4 o[4];
#pragma unroll
    for (int dt = 0; dt < 4; ++dt) o[dt] = (f32x4){0.f, 0.f, 0.f, 0.f};

    const int nt = blockIdx.x + 9;          // tiles of 64 keys, last = i0+512
    const int basew = 48 - w * 16;          // wave's band base in P_s

    bf16x8 kreg[2], vreg[2], preg[4];

    auto load_tile = [&](int t0) {
        const int j0 = t0 * 64;
#pragma unroll
        for (int e = 0; e < 2; ++e) {
            int lin = t + e * 256;
            int jr = lin >> 3, c8 = (lin & 7) * 8;
            const bf16* base = kv + (size_t)((j0 + jr) * BSZ + b) * 2048 + h * HD + c8;
            kreg[e] = *(const bf16x8*)base;
            vreg[e] = *(const bf16x8*)(base + 1024);
        }
        const int pbase = j0 - i0 + 448;
#pragma unroll
        for (int e = 0; e < 4; ++e) {
            int lin = t + e * 256;
            int pr = lin >> 3, c8 = (lin & 7) * 8;
            int c = pbase + pr;
            if (c < TOT) preg[e] = *(const bf16x8*)(pb + (size_t)c * DIN + h * HD + c8);
            else {
#pragma unroll
                for (int m = 0; m < 8; ++m) preg[e][m] = (bf16)0.f;
            }
        }
    };

    auto store_tile = [&]() {
#pragma unroll
        for (int e = 0; e < 2; ++e) {
            int lin = t + e * 256;
            int jr = lin >> 3, c8 = (lin & 7) * 8;
            *(bf16x8*)&K_s[jr][c8] = kreg[e];
            int jrot = (jr + (lin & 7) * 8) & 63;   // rotate j by 8*(d>>3)
#pragma unroll
            for (int mm = 0; mm < 8; ++mm) V_s[c8 + mm][jrot] = vreg[e][mm];
        }
#pragma unroll
        for (int e = 0; e < 4; ++e) {
            int lin = t + e * 256;
            int pr = lin >> 3, c8 = (lin & 7) * 8;
            *(bf16x8*)&P_s[pr][c8] = preg[e];
        }
    };

    load_tile(0);
    for (int t0 = 0; t0 < nt; ++t0) {
        const int j0 = t0 * 64;
        __syncthreads();                 // previous tile's LDS reads done
        store_tile();
        __syncthreads();                 // staged data visible
        if (t0 + 1 < nt) load_tile(t0 + 1);   // prefetch overlaps compute

        // ---- content scores S^T = K . QU^T ----
        f32x4 st[4];
#pragma unroll
        for (int ct = 0; ct < 4; ++ct) {
            f32x4 a = (f32x4){0.f, 0.f, 0.f, 0.f};
#pragma unroll
            for (int kk = 0; kk < 2; ++kk) {
                bf16x8 kf = *(const bf16x8*)&K_s[ct * 16 + li][kk * 32 + hi * 8];
                a = MFMA16(kf, qu[kk], a);
            }
            st[ct] = a;
        }

        // ---- raw position scores R^T = P_band . QV^T -> wave scratch (bf16) ----
#pragma unroll
        for (int pt = 0; pt < 5; ++pt) {
            f32x4 a = (f32x4){0.f, 0.f, 0.f, 0.f};
#pragma unroll
            for (int kk = 0; kk < 2; ++kk) {
                bf16x8 pf = *(const bf16x8*)&P_s[basew + pt * 16 + li][kk * 32 + hi * 8];
                a = MFMA16(pf, qv[kk], a);
            }
#pragma unroll
            for (int r = 0; r < 4; ++r) rsc[(pt * 16 + hi * 4 + r) * 18 + li] = (bf16)a[r];
        }

        // ---- assemble S (shifted pos add), scale, mask ----
        float pr_[4][4];
        float rowmax = -1e30f;
        const int lim = i0 + w * 16 + li + PREV - j0;   // mask iff lj > lim
#pragma unroll
        for (int ct = 0; ct < 4; ++ct)
#pragma unroll
            for (int r = 0; r < 4; ++r) {
                int lj = ct * 16 + hi * 4 + r;
                float sv = (st[ct][r] + (float)rsc[(lj + 15 - li) * 18 + li]) * 0.125f;
                if (lj > lim) sv = -1e30f;
                pr_[ct][r] = sv;
                rowmax = fmaxf(rowmax, sv);
            }
        rowmax = fmaxf(rowmax, __shfl_xor(rowmax, 16));
        rowmax = fmaxf(rowmax, __shfl_xor(rowmax, 32));

        // ---- defer-max online softmax ----
        if (!__all(rowmax - mrun <= 8.f)) {
            float newm = fmaxf(mrun, rowmax);
            float fsc = __expf(mrun - newm);
            float fr[4];
#pragma unroll
            for (int r = 0; r < 4; ++r) fr[r] = __shfl(fsc, hi * 4 + r);
#pragma unroll
            for (int dt = 0; dt < 4; ++dt)
#pragma unroll
                for (int r = 0; r < 4; ++r) o[dt][r] *= fr[r];
            lrun *= fsc;
            mrun = newm;
        }

        float rowsum = 0.f;
#pragma unroll
        for (int ct = 0; ct < 4; ++ct)
#pragma unroll
            for (int r = 0; r < 4; ++r) {
                float p = __expf(pr_[ct][r] - mrun);
                pr_[ct][r] = p;
                rowsum += p;
            }

        // ---- write probabilities bf16 to wave scratch (overlays R^T) ----
#pragma unroll
        for (int ct = 0; ct < 4; ++ct)
#pragma unroll
            for (int rr = 0; rr < 2; ++rr) {
                unsigned int pw = (unsigned int)bfbits(pr_[ct][2 * rr]) |
                                  ((unsigned int)bfbits(pr_[ct][2 * rr + 1]) << 16);
                *(unsigned int*)&ps[li * 72 + ct * 16 + hi * 4 + 2 * rr] = pw;
            }

        rowsum += __shfl_xor(rowsum, 16);
        rowsum += __shfl_xor(rowsum, 32);
        lrun += rowsum;

        // ---- PV: O += P . V ----
#pragma unroll
        for (int kk = 0; kk < 2; ++kk) {
            bf16x8 pa = *(const bf16x8*)&ps[li * 72 + kk * 32 + hi * 8];
#pragma unroll
            for (int dt = 0; dt < 4; ++dt) {
                int d = dt * 16 + li;
                bf16x8 vf = *(const bf16x8*)&V_s[d][(kk * 32 + hi * 8 + (d >> 3) * 8) & 63];
                o[dt] = MFMA16(pa, vf, o[dt]);
            }
        }
    }

    // ---- epilogue: normalize and store ----
    float lr[4];
#pragma unroll
    for (int r = 0; r < 4; ++r) lr[r] = __shfl(lrun, hi * 4 + r);
#pragma unroll
    for (int dt = 0; dt < 4; ++dt)
#pragma unroll
        for (int r = 0; r < 4; ++r) {
            int row = i0 + w * 16 + hi * 4 + r;
            awv[(size_t)(row * BSZ + b) * DIN + h * HD + dt * 16 + li] = (bf16)(o[dt][r] / lr[r]);
        }
}

// ---------------------------------------------------------------------------
// In-place LayerNorm over last dim (1024). One block per row.
// ---------------------------------------------------------------------------
__global__ __launch_bounds__(256) void ln_f32(
    float* __restrict__ out, const float* __restrict__ gamma, const float* __restrict__ beta)
{
    const int row = blockIdx.x;
    const int t = threadIdx.x;
    float4 x = *(float4*)(out + (size_t)row * DIN + t * 4);
    float s  = x.x + x.y + x.z + x.w;
    float ss = x.x * x.x + x.y * x.y + x.z * x.z + x.w * x.w;
#pragma unroll
    for (int wd = 1; wd < 64; wd <<= 1) { s += __shfl_xor(s, wd); ss += __shfl_xor(ss, wd); }
    __shared__ float sbuf[4], ssbuf[4];
    const int wave = t >> 6, lanei = t & 63;
    if (lanei == 0) { sbuf[wave] = s; ssbuf[wave] = ss; }
    __syncthreads();
    s  = sbuf[0] + sbuf[1] + sbuf[2] + sbuf[3];
    ss = ssbuf[0] + ssbuf[1] + ssbuf[2] + ssbuf[3];
    const float mu   = s * (1.f / DIN);
    const float var  = ss * (1.f / DIN) - mu * mu;
    const float rstd = rsqrtf(var + 1e-5f);
    float4 g  = *(const float4*)(gamma + t * 4);
    float4 bb = *(const float4*)(beta + t * 4);
    float4 y;
    y.x = (x.x - mu) * rstd * g.x + bb.x;
    y.y = (x.y - mu) * rstd * g.y + bb.y;
    y.z = (x.z - mu) * rstd * g.z + bb.z;
    y.w = (x.w - mu) * rstd * g.w + bb.w;
    *(float4*)(out + (size_t)row * DIN + t * 4) = y;
}

// ---------------------------------------------------------------------------
extern "C" void kernel_launch(void* const* d_in, const int* in_sizes, int n_in,
                              void* d_out, int out_size, void* d_ws, size_t ws_size,
                              hipStream_t stream)
{
    const float* input_ = (const float*)d_in[0];
    const float* pos    = (const float*)d_in[1];
    const float* memory = (const float*)d_in[2];
    const float* u      = (const float*)d_in[3];
    const float* v      = (const float*)d_in[4];
    // d_in[5] = mask: computed analytically (j > i + PREV)
    const float* W_kv   = (const float*)d_in[6];
    const float* W_q    = (const float*)d_in[7];
    const float* W_p    = (const float*)d_in[8];
    const float* W_out  = (const float*)d_in[9];
    const float* gamma  = (const float*)d_in[10];
    const float* beta   = (const float*)d_in[11];

    bf16* iwm  = (bf16*)d_ws;                      // [8192][1024]  (memory ; input)
    bf16* kvb  = iwm  + (size_t)8192 * 1024;       // [8192][2048]  k | v
    bf16* qbf  = kvb  + (size_t)8192 * 2048;       // [4096][1024]
    bf16* pbf  = qbf  + (size_t)4096 * 1024;       // [1024][1024]
    bf16* posb = pbf  + (size_t)1024 * 1024;       // [1024][1024]
    bf16* wkv  = posb + (size_t)1024 * 1024;       // [2048][1024]  W_kv^T
    bf16* wq   = wkv  + (size_t)2048 * 1024;       // [1024][1024]
    bf16* wp   = wq   + (size_t)1024 * 1024;
    bf16* wo   = wp   + (size_t)1024 * 1024;
    bf16* awvb = wo   + (size_t)1024 * 1024;       // [4096][1024]
    float* outf = (float*)d_out;

    // casts / transposes
    cast_cat<<<8192, 256, 0, stream>>>(memory, 4194304, input_, iwm);
    cast_cat<<<1024, 256, 0, stream>>>(pos, 1048576, pos, posb);
    transcast_all<<<dim3(160, 32), 256, 0, stream>>>(W_kv, W_q, W_p, W_out, wkv, wq, wp, wo);

    // projections (bf16 out)
    gemm_mfma<0><<<dim3(16, 64), 256, 0, stream>>>(iwm, wkv, nullptr, kvb, nullptr, 8192, 2048, 1024);
    gemm_mfma<0><<<dim3(8, 32), 256, 0, stream>>>(iwm + (size_t)4096 * 1024, wq, nullptr, qbf, nullptr, 4096, 1024, 1024);
    gemm_mfma<0><<<dim3(8, 8),  256, 0, stream>>>(posb, wp, nullptr, pbf, nullptr, 1024, 1024, 1024);

    // fused attention
    attn_mfma<<<dim3(8, 8, 16), 256, 0, stream>>>(kvb, qbf, pbf, u, v, awvb);

    // out projection + residual (f32), then LayerNorm
    gemm_mfma<1><<<dim3(8, 32), 256, 0, stream>>>(awvb, wo, input_, nullptr, outf, 4096, 1024, 1024);
    ln_f32<<<4096, 256, 0, stream>>>(outf, gamma, beta);
}

// Round 4
// 214.447 us; speedup vs baseline: 55.7040x; 1.0713x over previous
//
#include <hip/hip_runtime.h>
#include <math.h>

#define SEQ  512
#define PREV 512
#define TOT  1024
#define BSZ  8
#define DIN  1024
#define NH   16
#define HD   64

typedef __bf16 bf16;
typedef __bf16 bf16x8 __attribute__((ext_vector_type(8)));
typedef float  f32x4  __attribute__((ext_vector_type(4)));

__device__ __forceinline__ f32x4 MFMA16(bf16x8 a, bf16x8 b, f32x4 c) {
    return __builtin_amdgcn_mfma_f32_16x16x32_bf16(a, b, c, 0, 0, 0);
}

#define GLOAD16(g, l) __builtin_amdgcn_global_load_lds( \
    (const __attribute__((address_space(1))) void*)(g), \
    (__attribute__((address_space(3))) void*)(l), 16, 0, 0)

__device__ __forceinline__ unsigned short bfbits(float x) {
    return __builtin_bit_cast(unsigned short, (bf16)x);
}

// ---------------------------------------------------------------------------
// cast f32 -> bf16, two concatenated sources (A then B).
// ---------------------------------------------------------------------------
__global__ __launch_bounds__(256) void cast_cat(
    const float* __restrict__ A, int nA, const float* __restrict__ B,
    bf16* __restrict__ out)
{
    int e4 = (blockIdx.x * 256 + threadIdx.x) * 4;
    float4 x = (e4 < nA) ? *(const float4*)(A + e4) : *(const float4*)(B + e4 - nA);
    union { bf16 h[4]; ushort4 u4; } pk;
    pk.h[0] = (bf16)x.x; pk.h[1] = (bf16)x.y; pk.h[2] = (bf16)x.z; pk.h[3] = (bf16)x.w;
    *(ushort4*)(out + e4) = pk.u4;
}

// ---------------------------------------------------------------------------
// merged transpose+cast for all 4 weights: Wt[n][k] = W[k][n]. K=1024.
// ---------------------------------------------------------------------------
__global__ __launch_bounds__(256) void transcast_all(
    const float* __restrict__ W_kv, const float* __restrict__ W_q,
    const float* __restrict__ W_p,  const float* __restrict__ W_out,
    bf16* __restrict__ wkv, bf16* __restrict__ wq,
    bf16* __restrict__ wp,  bf16* __restrict__ wo)
{
    __shared__ float tile[32][33];
    const int bx = blockIdx.x;
    const float* W; bf16* Wt; int N, bn;
    if (bx < 64)       { W = W_kv;  Wt = wkv; N = 2048; bn = bx * 32; }
    else if (bx < 96)  { W = W_q;   Wt = wq;  N = 1024; bn = (bx - 64) * 32; }
    else if (bx < 128) { W = W_p;   Wt = wp;  N = 1024; bn = (bx - 96) * 32; }
    else               { W = W_out; Wt = wo;  N = 1024; bn = (bx - 128) * 32; }
    const int t = threadIdx.x;
    const int bk = blockIdx.y * 32;
    const int r = t >> 3, c4 = (t & 7) * 4;
    float4 x = *(const float4*)(W + (size_t)(bk + r) * N + bn + c4);
    tile[r][c4 + 0] = x.x; tile[r][c4 + 1] = x.y;
    tile[r][c4 + 2] = x.z; tile[r][c4 + 3] = x.w;
    __syncthreads();
    union { bf16 h[4]; ushort4 u4; } pk;
#pragma unroll
    for (int i = 0; i < 4; ++i) pk.h[i] = (bf16)tile[c4 + i][r];
    *(ushort4*)(Wt + (size_t)(bn + r) * 1024 + bk + c4) = pk.u4;
}

// ---------------------------------------------------------------------------
// bf16 MFMA GEMM: C[M][N] = A[M][K] @ B^T (B as Bt[N][K]). 128x128, BK=64.
// ---------------------------------------------------------------------------
template<int FOUT>
__global__ __launch_bounds__(256) void gemm_mfma(
    const bf16* __restrict__ A, const bf16* __restrict__ Bt,
    const float* __restrict__ Rres, bf16* __restrict__ Cb,
    float* __restrict__ Cf, int M, int N, int K)
{
    __shared__ __align__(16) bf16 A_s[128 * 64];
    __shared__ __align__(16) bf16 B_s[128 * 64];
    const int t = threadIdx.x;
    const int w = t >> 6, lane = t & 63;
    const int li = lane & 15, hi = lane >> 4;
    const int wr = w >> 1, wc = w & 1;
    const int bm = blockIdx.y * 128, bn = blockIdx.x * 128;
    const int l3 = lane >> 3, l7 = lane & 7;
    const int srcoct = ((l7 ^ l3) * 8);

    f32x4 acc[4][4];
#pragma unroll
    for (int m = 0; m < 4; ++m)
#pragma unroll
        for (int n = 0; n < 4; ++n) acc[m][n] = (f32x4){0.f, 0.f, 0.f, 0.f};

    auto stage = [&](int k0) {
#pragma unroll
        for (int i = 0; i < 4; ++i) {
            int c = w * 4 + i;
            const bf16* ga = A + (size_t)(bm + c * 8 + l3) * K + k0 + srcoct;
            GLOAD16(ga, &A_s[c * 512]);
            const bf16* gb = Bt + (size_t)(bn + c * 8 + l3) * K + k0 + srcoct;
            GLOAD16(gb, &B_s[c * 512]);
        }
    };

    stage(0);
    const int nk = K >> 6;
    for (int ks = 0; ks < nk; ++ks) {
        __syncthreads();
#pragma unroll
        for (int kk = 0; kk < 2; ++kk) {
            bf16x8 af[4], bfr[4];
#pragma unroll
            for (int m = 0; m < 4; ++m) {
                int row = wr * 64 + m * 16 + li;
                af[m] = *(const bf16x8*)&A_s[row * 64 + ((kk * 32 + hi * 8) ^ ((row & 7) * 8))];
            }
#pragma unroll
            for (int n = 0; n < 4; ++n) {
                int row = wc * 64 + n * 16 + li;
                bfr[n] = *(const bf16x8*)&B_s[row * 64 + ((kk * 32 + hi * 8) ^ ((row & 7) * 8))];
            }
#pragma unroll
            for (int m = 0; m < 4; ++m)
#pragma unroll
                for (int n = 0; n < 4; ++n)
                    acc[m][n] = MFMA16(af[m], bfr[n], acc[m][n]);
        }
        __syncthreads();
        if (ks + 1 < nk) stage((ks + 1) << 6);
    }

#pragma unroll
    for (int m = 0; m < 4; ++m)
#pragma unroll
        for (int n = 0; n < 4; ++n)
#pragma unroll
            for (int r = 0; r < 4; ++r) {
                int row = bm + wr * 64 + m * 16 + hi * 4 + r;
                int col = bn + wc * 64 + n * 16 + li;
                size_t off = (size_t)row * N + col;
                if (FOUT) Cf[off] = acc[m][n][r] + Rres[off];
                else      Cb[off] = (bf16)acc[m][n][r];
            }
}

// ---------------------------------------------------------------------------
// Fused flash attention (Transformer-XL rel-pos), bf16 MFMA 16x16x32.
// Block = (128 q-rows, b, h), 8 waves (512 thr); wave owns 16 q-rows.
// Swapped QK^T: S^T = K.QU^T so lane li owns one q-row.
// P staged in a 256-row LDS ring, 64 new rows/tile. 2-deep ping-pong
// register prefetch for K/V/P (static buffers, unrolled pair loop).
// ---------------------------------------------------------------------------
__global__ __launch_bounds__(512, 4) void attn_mfma(
    const bf16* __restrict__ kv, const bf16* __restrict__ qb,
    const bf16* __restrict__ pb, const float* __restrict__ u,
    const float* __restrict__ v, bf16* __restrict__ awv)
{
    // complementary pairing: co-resident pairs (n, n+256) differ only in z,
    // so alternate bi order by z to make per-CU work ~constant.
    const int bi = (blockIdx.z & 1) ? (3 - blockIdx.x) : blockIdx.x;
    const int i0 = bi * 128;
    const int b  = blockIdx.y;
    const int h  = blockIdx.z;
    const int t  = threadIdx.x;
    const int w  = t >> 6;
    const int lane = t & 63;
    const int li = lane & 15, hi = lane >> 4;

    __shared__ __align__(16) bf16 K_s[64][72];
    __shared__ __align__(16) bf16 V_s[64][72];    // V^T with j-rotation by (d>>3)
    __shared__ __align__(16) bf16 P_s[256][72];   // ring over global P rows
    __shared__ __align__(16) char SCR[8][2880];   // per-wave R^T [80][18] bf16 / Ps [16][72] bf16

    bf16* rsc = (bf16*)SCR[w];
    bf16* ps  = (bf16*)SCR[w];

    const int jr = t >> 3;            // 0..63 (row within tile)
    const int a8 = (t & 7) * 8;       // d-octet
    const int pbase0 = 384 - i0;      // P band base (global row) at tile 0
    const int nt = 2 * bi + 10;       // tiles (always even)

    bf16x8 zero8;
#pragma unroll
    for (int m = 0; m < 8; ++m) zero8[m] = (bf16)0.f;

    // ---- Q fragments (+u / +v) ----
    bf16x8 qu[2], qv[2];
    {
        const int qrow = (i0 + w * 16 + li) * BSZ + b;
#pragma unroll
        for (int kk = 0; kk < 2; ++kk) {
            bf16x8 q8 = *(const bf16x8*)(qb + (size_t)qrow * DIN + h * HD + kk * 32 + hi * 8);
            const float* up = u + h * HD + kk * 32 + hi * 8;
            const float* vp = v + h * HD + kk * 32 + hi * 8;
#pragma unroll
            for (int m = 0; m < 8; ++m) {
                float qf = (float)q8[m];
                qu[kk][m] = (bf16)(qf + up[m]);
                qv[kk][m] = (bf16)(qf + vp[m]);
            }
        }
    }

    // ---- initial P fill: bottom 128 rows of tile-0 band (rows always < TOT) ----
    {
        int g0 = pbase0 + jr;
        bf16x8 pi0 = *(const bf16x8*)(pb + (size_t)g0 * DIN + h * HD + a8);
        bf16x8 pi1 = *(const bf16x8*)(pb + (size_t)(g0 + 64) * DIN + h * HD + a8);
        *(bf16x8*)&P_s[g0 & 255][a8] = pi0;
        *(bf16x8*)&P_s[(g0 + 64) & 255][a8] = pi1;
    }

    // ---- 2-deep prefetch (static ping-pong regs) ----
    bf16x8 k0r, v0r, p0r, k1r, v1r, p1r;
    {
        const bf16* base0 = kv + ((size_t)((0 * 64 + jr) * BSZ + b) * 2048) + h * HD + a8;
        k0r = *(const bf16x8*)base0;
        v0r = *(const bf16x8*)(base0 + 1024);
        int g = pbase0 + 128 + jr;
        p0r = (g < TOT) ? *(const bf16x8*)(pb + (size_t)g * DIN + h * HD + a8) : zero8;
        const bf16* base1 = kv + ((size_t)((64 + jr) * BSZ + b) * 2048) + h * HD + a8;
        k1r = *(const bf16x8*)base1;
        v1r = *(const bf16x8*)(base1 + 1024);
        g += 64;
        p1r = (g < TOT) ? *(const bf16x8*)(pb + (size_t)g * DIN + h * HD + a8) : zero8;
    }

    float mrun = -1e30f, lrun = 0.f;
    f32x4 o[4];
#pragma unroll
    for (int dt = 0; dt < 4; ++dt) o[dt] = (f32x4){0.f, 0.f, 0.f, 0.f};

    auto tile_body = [&](int tt, bf16x8& kc, bf16x8& vc, bf16x8& pc) {
        const int j0 = tt * 64;
        __syncthreads();                    // previous tile's LDS reads done
        // ---- store staged tile ----
        *(bf16x8*)&K_s[jr][a8] = kc;
        {
            int jrot = (jr + a8) & 63;      // rotate j by 8*(d>>3)
#pragma unroll
            for (int mm = 0; mm < 8; ++mm) V_s[a8 + mm][jrot] = vc[mm];
        }
        *(bf16x8*)&P_s[(pbase0 + j0 + 128 + jr) & 255][a8] = pc;
        __syncthreads();                    // staged data visible
        // ---- prefetch tile tt+2 into same regs ----
        if (tt + 2 < nt) {
            const int j2 = j0 + 128;
            const bf16* base = kv + ((size_t)((j2 + jr) * BSZ + b) * 2048) + h * HD + a8;
            kc = *(const bf16x8*)base;
            vc = *(const bf16x8*)(base + 1024);
            int g = pbase0 + j2 + 128 + jr;
            pc = (g < TOT) ? *(const bf16x8*)(pb + (size_t)g * DIN + h * HD + a8) : zero8;
        }

        // ---- content scores S^T = K . QU^T ----
        f32x4 st[4];
#pragma unroll
        for (int ct = 0; ct < 4; ++ct) {
            f32x4 a = (f32x4){0.f, 0.f, 0.f, 0.f};
#pragma unroll
            for (int kk = 0; kk < 2; ++kk) {
                bf16x8 kf = *(const bf16x8*)&K_s[ct * 16 + li][kk * 32 + hi * 8];
                a = MFMA16(kf, qu[kk], a);
            }
            st[ct] = a;
        }

        // ---- raw position scores R^T = P_band . QV^T -> wave scratch (bf16) ----
        const int prb = pbase0 + j0 + 112 - w * 16;   // wave band base (global row)
#pragma unroll
        for (int pt = 0; pt < 5; ++pt) {
            f32x4 a = (f32x4){0.f, 0.f, 0.f, 0.f};
#pragma unroll
            for (int kk = 0; kk < 2; ++kk) {
                bf16x8 pf = *(const bf16x8*)&P_s[(prb + pt * 16 + li) & 255][kk * 32 + hi * 8];
                a = MFMA16(pf, qv[kk], a);
            }
#pragma unroll
            for (int r = 0; r < 4; ++r) rsc[(pt * 16 + hi * 4 + r) * 18 + li] = (bf16)a[r];
        }

        // ---- assemble S (shifted pos add), scale, mask ----
        float pr_[4][4];
        float rowmax = -1e30f;
        const int lim = i0 + w * 16 + li + PREV - j0;   // mask iff lj > lim
#pragma unroll
        for (int ct = 0; ct < 4; ++ct)
#pragma unroll
            for (int r = 0; r < 4; ++r) {
                int lj = ct * 16 + hi * 4 + r;
                float sv = (st[ct][r] + (float)rsc[(lj + 15 - li) * 18 + li]) * 0.125f;
                if (lj > lim) sv = -1e30f;
                pr_[ct][r] = sv;
                rowmax = fmaxf(rowmax, sv);
            }
        rowmax = fmaxf(rowmax, __shfl_xor(rowmax, 16));
        rowmax = fmaxf(rowmax, __shfl_xor(rowmax, 32));

        // ---- defer-max online softmax ----
        if (!__all(rowmax - mrun <= 8.f)) {
            float newm = fmaxf(mrun, rowmax);
            float fsc = __expf(mrun - newm);
            float fr[4];
#pragma unroll
            for (int r = 0; r < 4; ++r) fr[r] = __shfl(fsc, hi * 4 + r);
#pragma unroll
            for (int dt = 0; dt < 4; ++dt)
#pragma unroll
                for (int r = 0; r < 4; ++r) o[dt][r] *= fr[r];
            lrun *= fsc;
            mrun = newm;
        }

        float rowsum = 0.f;
#pragma unroll
        for (int ct = 0; ct < 4; ++ct)
#pragma unroll
            for (int r = 0; r < 4; ++r) {
                float p = __expf(pr_[ct][r] - mrun);
                pr_[ct][r] = p;
                rowsum += p;
            }

        // ---- write probabilities bf16 to wave scratch (overlays R^T) ----
#pragma unroll
        for (int ct = 0; ct < 4; ++ct)
#pragma unroll
            for (int rr = 0; rr < 2; ++rr) {
                unsigned int pw = (unsigned int)bfbits(pr_[ct][2 * rr]) |
                                  ((unsigned int)bfbits(pr_[ct][2 * rr + 1]) << 16);
                *(unsigned int*)&ps[li * 72 + ct * 16 + hi * 4 + 2 * rr] = pw;
            }

        rowsum += __shfl_xor(rowsum, 16);
        rowsum += __shfl_xor(rowsum, 32);
        lrun += rowsum;

        // ---- PV: O += P . V ----
#pragma unroll
        for (int kk = 0; kk < 2; ++kk) {
            bf16x8 pa = *(const bf16x8*)&ps[li * 72 + kk * 32 + hi * 8];
#pragma unroll
            for (int dt = 0; dt < 4; ++dt) {
                int d = dt * 16 + li;
                bf16x8 vf = *(const bf16x8*)&V_s[d][(kk * 32 + hi * 8 + (d >> 3) * 8) & 63];
                o[dt] = MFMA16(pa, vf, o[dt]);
            }
        }
    };

    // nt is even: process tiles in pairs with static ping-pong buffers
    for (int tp = 0; tp < nt; tp += 2) {
        tile_body(tp,     k0r, v0r, p0r);
        tile_body(tp + 1, k1r, v1r, p1r);
    }

    // ---- epilogue: normalize and store ----
    float lr[4];
#pragma unroll
    for (int r = 0; r < 4; ++r) lr[r] = __shfl(lrun, hi * 4 + r);
#pragma unroll
    for (int dt = 0; dt < 4; ++dt)
#pragma unroll
        for (int r = 0; r < 4; ++r) {
            int row = i0 + w * 16 + hi * 4 + r;
            awv[(size_t)(row * BSZ + b) * DIN + h * HD + dt * 16 + li] = (bf16)(o[dt][r] / lr[r]);
        }
}

// ---------------------------------------------------------------------------
// In-place LayerNorm over last dim (1024). One block per row.
// ---------------------------------------------------------------------------
__global__ __launch_bounds__(256) void ln_f32(
    float* __restrict__ out, const float* __restrict__ gamma, const float* __restrict__ beta)
{
    const int row = blockIdx.x;
    const int t = threadIdx.x;
    float4 x = *(float4*)(out + (size_t)row * DIN + t * 4);
    float s  = x.x + x.y + x.z + x.w;
    float ss = x.x * x.x + x.y * x.y + x.z * x.z + x.w * x.w;
#pragma unroll
    for (int wd = 1; wd < 64; wd <<= 1) { s += __shfl_xor(s, wd); ss += __shfl_xor(ss, wd); }
    __shared__ float sbuf[4], ssbuf[4];
    const int wave = t >> 6, lanei = t & 63;
    if (lanei == 0) { sbuf[wave] = s; ssbuf[wave] = ss; }
    __syncthreads();
    s  = sbuf[0] + sbuf[1] + sbuf[2] + sbuf[3];
    ss = ssbuf[0] + ssbuf[1] + ssbuf[2] + ssbuf[3];
    const float mu   = s * (1.f / DIN);
    const float var  = ss * (1.f / DIN) - mu * mu;
    const float rstd = rsqrtf(var + 1e-5f);
    float4 g  = *(const float4*)(gamma + t * 4);
    float4 bb = *(const float4*)(beta + t * 4);
    float4 y;
    y.x = (x.x - mu) * rstd * g.x + bb.x;
    y.y = (x.y - mu) * rstd * g.y + bb.y;
    y.z = (x.z - mu) * rstd * g.z + bb.z;
    y.w = (x.w - mu) * rstd * g.w + bb.w;
    *(float4*)(out + (size_t)row * DIN + t * 4) = y;
}

// ---------------------------------------------------------------------------
extern "C" void kernel_launch(void* const* d_in, const int* in_sizes, int n_in,
                              void* d_out, int out_size, void* d_ws, size_t ws_size,
                              hipStream_t stream)
{
    const float* input_ = (const float*)d_in[0];
    const float* pos    = (const float*)d_in[1];
    const float* memory = (const float*)d_in[2];
    const float* u      = (const float*)d_in[3];
    const float* v      = (const float*)d_in[4];
    // d_in[5] = mask: computed analytically (j > i + PREV)
    const float* W_kv   = (const float*)d_in[6];
    const float* W_q    = (const float*)d_in[7];
    const float* W_p    = (const float*)d_in[8];
    const float* W_out  = (const float*)d_in[9];
    const float* gamma  = (const float*)d_in[10];
    const float* beta   = (const float*)d_in[11];

    bf16* iwm  = (bf16*)d_ws;                      // [8192][1024]  (memory ; input)
    bf16* kvb  = iwm  + (size_t)8192 * 1024;       // [8192][2048]  k | v
    bf16* qbf  = kvb  + (size_t)8192 * 2048;       // [4096][1024]
    bf16* pbf  = qbf  + (size_t)4096 * 1024;       // [1024][1024]
    bf16* posb = pbf  + (size_t)1024 * 1024;       // [1024][1024]
    bf16* wkv  = posb + (size_t)1024 * 1024;       // [2048][1024]  W_kv^T
    bf16* wq   = wkv  + (size_t)2048 * 1024;       // [1024][1024]
    bf16* wp   = wq   + (size_t)1024 * 1024;
    bf16* wo   = wp   + (size_t)1024 * 1024;
    bf16* awvb = wo   + (size_t)1024 * 1024;       // [4096][1024]
    float* outf = (float*)d_out;

    // casts / transposes
    cast_cat<<<8192, 256, 0, stream>>>(memory, 4194304, input_, iwm);
    cast_cat<<<1024, 256, 0, stream>>>(pos, 1048576, pos, posb);
    transcast_all<<<dim3(160, 32), 256, 0, stream>>>(W_kv, W_q, W_p, W_out, wkv, wq, wp, wo);

    // projections (bf16 out)
    gemm_mfma<0><<<dim3(16, 64), 256, 0, stream>>>(iwm, wkv, nullptr, kvb, nullptr, 8192, 2048, 1024);
    gemm_mfma<0><<<dim3(8, 32), 256, 0, stream>>>(iwm + (size_t)4096 * 1024, wq, nullptr, qbf, nullptr, 4096, 1024, 1024);
    gemm_mfma<0><<<dim3(8, 8),  256, 0, stream>>>(posb, wp, nullptr, pbf, nullptr, 1024, 1024, 1024);

    // fused attention: 4 q-blocks x 8 b x 16 h, 512 threads
    attn_mfma<<<dim3(4, 8, 16), 512, 0, stream>>>(kvb, qbf, pbf, u, v, awvb);

    // out projection + residual (f32), then LayerNorm
    gemm_mfma<1><<<dim3(8, 32), 256, 0, stream>>>(awvb, wo, input_, nullptr, outf, 4096, 1024, 1024);
    ln_f32<<<4096, 256, 0, stream>>>(outf, gamma, beta);
}

// Round 5
// 205.338 us; speedup vs baseline: 58.1751x; 1.0444x over previous
//
#include <hip/hip_runtime.h>
#include <math.h>

#define SEQ  512
#define PREV 512
#define TOT  1024
#define BSZ  8
#define DIN  1024
#define NH   16
#define HD   64

typedef __bf16 bf16;
typedef __bf16 bf16x8 __attribute__((ext_vector_type(8)));
typedef float  f32x4  __attribute__((ext_vector_type(4)));
typedef float  f32x16 __attribute__((ext_vector_type(16)));
typedef unsigned int u32;
typedef u32 u32x2 __attribute__((ext_vector_type(2)));

__device__ __forceinline__ f32x4 MFMA16(bf16x8 a, bf16x8 b, f32x4 c) {
    return __builtin_amdgcn_mfma_f32_16x16x32_bf16(a, b, c, 0, 0, 0);
}
__device__ __forceinline__ f32x16 MFMA32(bf16x8 a, bf16x8 b, f32x16 c) {
    return __builtin_amdgcn_mfma_f32_32x32x16_bf16(a, b, c, 0, 0, 0);
}

#define GLOAD16(g, l) __builtin_amdgcn_global_load_lds( \
    (const __attribute__((address_space(1))) void*)(g), \
    (__attribute__((address_space(3))) void*)(l), 16, 0, 0)

__device__ __forceinline__ unsigned short bfbits(float x) {
    return __builtin_bit_cast(unsigned short, (bf16)x);
}
__device__ __forceinline__ float bf2f(u32 bits16) {   // low 16 bits -> f32
    return __builtin_bit_cast(float, bits16 << 16);
}

// ---------------------------------------------------------------------------
// cast f32 -> bf16, two concatenated sources (A then B).
// ---------------------------------------------------------------------------
__global__ __launch_bounds__(256) void cast_cat(
    const float* __restrict__ A, int nA, const float* __restrict__ B,
    bf16* __restrict__ out)
{
    int e4 = (blockIdx.x * 256 + threadIdx.x) * 4;
    float4 x = (e4 < nA) ? *(const float4*)(A + e4) : *(const float4*)(B + e4 - nA);
    union { bf16 h[4]; ushort4 u4; } pk;
    pk.h[0] = (bf16)x.x; pk.h[1] = (bf16)x.y; pk.h[2] = (bf16)x.z; pk.h[3] = (bf16)x.w;
    *(ushort4*)(out + e4) = pk.u4;
}

// ---------------------------------------------------------------------------
// merged transpose+cast for all 4 weights: Wt[n][k] = W[k][n]. K=1024.
// ---------------------------------------------------------------------------
__global__ __launch_bounds__(256) void transcast_all(
    const float* __restrict__ W_kv, const float* __restrict__ W_q,
    const float* __restrict__ W_p,  const float* __restrict__ W_out,
    bf16* __restrict__ wkv, bf16* __restrict__ wq,
    bf16* __restrict__ wp,  bf16* __restrict__ wo)
{
    __shared__ float tile[32][33];
    const int bx = blockIdx.x;
    const float* W; bf16* Wt; int N, bn;
    if (bx < 64)       { W = W_kv;  Wt = wkv; N = 2048; bn = bx * 32; }
    else if (bx < 96)  { W = W_q;   Wt = wq;  N = 1024; bn = (bx - 64) * 32; }
    else if (bx < 128) { W = W_p;   Wt = wp;  N = 1024; bn = (bx - 96) * 32; }
    else               { W = W_out; Wt = wo;  N = 1024; bn = (bx - 128) * 32; }
    const int t = threadIdx.x;
    const int bk = blockIdx.y * 32;
    const int r = t >> 3, c4 = (t & 7) * 4;
    float4 x = *(const float4*)(W + (size_t)(bk + r) * N + bn + c4);
    tile[r][c4 + 0] = x.x; tile[r][c4 + 1] = x.y;
    tile[r][c4 + 2] = x.z; tile[r][c4 + 3] = x.w;
    __syncthreads();
    union { bf16 h[4]; ushort4 u4; } pk;
#pragma unroll
    for (int i = 0; i < 4; ++i) pk.h[i] = (bf16)tile[c4 + i][r];
    *(ushort4*)(Wt + (size_t)(bn + r) * 1024 + bk + c4) = pk.u4;
}

// ---------------------------------------------------------------------------
// bf16 MFMA GEMM: C[M][N] = A[M][K] @ B^T (B as Bt[N][K]). 128x128, BK=64.
// ---------------------------------------------------------------------------
template<int FOUT>
__global__ __launch_bounds__(256) void gemm_mfma(
    const bf16* __restrict__ A, const bf16* __restrict__ Bt,
    const float* __restrict__ Rres, bf16* __restrict__ Cb,
    float* __restrict__ Cf, int M, int N, int K)
{
    __shared__ __align__(16) bf16 A_s[128 * 64];
    __shared__ __align__(16) bf16 B_s[128 * 64];
    const int t = threadIdx.x;
    const int w = t >> 6, lane = t & 63;
    const int li = lane & 15, hi = lane >> 4;
    const int wr = w >> 1, wc = w & 1;
    const int bm = blockIdx.y * 128, bn = blockIdx.x * 128;
    const int l3 = lane >> 3, l7 = lane & 7;
    const int srcoct = ((l7 ^ l3) * 8);

    f32x4 acc[4][4];
#pragma unroll
    for (int m = 0; m < 4; ++m)
#pragma unroll
        for (int n = 0; n < 4; ++n) acc[m][n] = (f32x4){0.f, 0.f, 0.f, 0.f};

    auto stage = [&](int k0) {
#pragma unroll
        for (int i = 0; i < 4; ++i) {
            int c = w * 4 + i;
            const bf16* ga = A + (size_t)(bm + c * 8 + l3) * K + k0 + srcoct;
            GLOAD16(ga, &A_s[c * 512]);
            const bf16* gb = Bt + (size_t)(bn + c * 8 + l3) * K + k0 + srcoct;
            GLOAD16(gb, &B_s[c * 512]);
        }
    };

    stage(0);
    const int nk = K >> 6;
    for (int ks = 0; ks < nk; ++ks) {
        __syncthreads();
#pragma unroll
        for (int kk = 0; kk < 2; ++kk) {
            bf16x8 af[4], bfr[4];
#pragma unroll
            for (int m = 0; m < 4; ++m) {
                int row = wr * 64 + m * 16 + li;
                af[m] = *(const bf16x8*)&A_s[row * 64 + ((kk * 32 + hi * 8) ^ ((row & 7) * 8))];
            }
#pragma unroll
            for (int n = 0; n < 4; ++n) {
                int row = wc * 64 + n * 16 + li;
                bfr[n] = *(const bf16x8*)&B_s[row * 64 + ((kk * 32 + hi * 8) ^ ((row & 7) * 8))];
            }
#pragma unroll
            for (int m = 0; m < 4; ++m)
#pragma unroll
                for (int n = 0; n < 4; ++n)
                    acc[m][n] = MFMA16(af[m], bfr[n], acc[m][n]);
        }
        __syncthreads();
        if (ks + 1 < nk) stage((ks + 1) << 6);
    }

#pragma unroll
    for (int m = 0; m < 4; ++m)
#pragma unroll
        for (int n = 0; n < 4; ++n)
#pragma unroll
            for (int r = 0; r < 4; ++r) {
                int row = bm + wr * 64 + m * 16 + hi * 4 + r;
                int col = bn + wc * 64 + n * 16 + li;
                size_t off = (size_t)row * N + col;
                if (FOUT) Cf[off] = acc[m][n][r] + Rres[off];
                else      Cb[off] = (bf16)acc[m][n][r];
            }
}

// ---------------------------------------------------------------------------
// Fused flash attention (Transformer-XL rel-pos), bf16 MFMA 32x32x16.
// Block = (128 q-rows, b, h), 4 waves (256 thr); wave owns 32 q-rows.
// Swapped QK^T: S^T = K.QU^T so lane ql = lane&31 owns one q-row.
// K_s/P_s: stride-64 rows + XOR-(row&7) swizzle, staged via global_load_lds
// with pre-swizzled source. V_s: [64][72] transposed with jrot (store 2-way).
// P: 4-chunk 256-row ring (64-aligned chunks); rows >= 1024 are exactly the
// masked region (j > i+512  <=>  P-row >= 1024) so stale ring data is safe.
// rel-shift scratch rscT[q=ql][sigma=Rloc]: aligned b64 quad stores
// (C-layout rows (r&3)+8(r>>2)+4hi2 -> 4-aligned), reads = 2 x b64 +
// 64-bit funnel shift by lane-constant phase (31-ql)&3.
// 3 raw barriers/tile: A (prev reads done) / B (staging visible, after
// vmcnt0+lgkmcnt0) / C (K & P reads done -> safe to issue next gloads).
// ---------------------------------------------------------------------------
__global__ __launch_bounds__(256, 2) void attn_mfma(
    const bf16* __restrict__ kv, const bf16* __restrict__ qb,
    const bf16* __restrict__ pb, const float* __restrict__ u,
    const float* __restrict__ v, bf16* __restrict__ awv)
{
    const int bi = (blockIdx.z & 1) ? (3 - blockIdx.x) : blockIdx.x;
    const int i0 = bi * 128;
    const int b  = blockIdx.y;
    const int h  = blockIdx.z;
    const int t  = threadIdx.x;
    const int w  = t >> 6;
    const int lane = t & 63;
    const int ql  = lane & 31;       // own q column (l31)
    const int hi2 = lane >> 5;       // k-split half

    __shared__ __align__(16) bf16 K_s[64 * 64];       // stride 64, XOR swizzle
    __shared__ __align__(16) bf16 V_s[64][72];        // V^T with jrot
    __shared__ __align__(16) bf16 P_s[256 * 64];      // ring, stride 64, XOR swizzle
    __shared__ __align__(16) char SCR[4][6912];       // per-wave rscT[32][108]bf16 / ps[32][72]bf16

    char* rsc = SCR[w];
    char* ps  = SCR[w];

    const int c8 = t & 7;            // 16B octet within row
    const int rq = t >> 3;           // 0..31 row within 32-row staging pass
    const int nt = 2 * bi + 10;      // 64-key tiles
    const int C0 = 384 - i0;         // P chunk-0 base row (64-aligned, >=0)

    // ---- prologue staging: V(0) reg loads first, then K(0), P chunks 0..2 ----
    bf16x8 vreg[2];
#pragma unroll
    for (int p = 0; p < 2; ++p)
        vreg[p] = *(const bf16x8*)(kv + (size_t)((p * 32 + rq) * BSZ + b) * 2048 + 1024 + h * HD + c8 * 8);
#pragma unroll
    for (int p = 0; p < 2; ++p)
        GLOAD16(kv + (size_t)((p * 32 + rq) * BSZ + b) * 2048 + h * HD + ((c8 ^ (rq & 7)) * 8),
                K_s + (p * 32 + rq) * 64 + c8 * 8);
#pragma unroll
    for (int cp = 0; cp < 6; ++cp) {
        int grow = C0 + cp * 32 + rq;
        GLOAD16(pb + (size_t)grow * DIN + h * HD + ((c8 ^ (rq & 7)) * 8),
                P_s + (grow & 255) * 64 + c8 * 8);
    }

    // ---- Q fragments (+u content / +v position) ----
    bf16x8 qu[4], qv[4];
    {
        const size_t qoff = ((size_t)(i0 + w * 32 + ql) * BSZ + b) * DIN + h * HD;
#pragma unroll
        for (int kk = 0; kk < 4; ++kk) {
            bf16x8 q8 = *(const bf16x8*)(qb + qoff + kk * 16 + hi2 * 8);
            const float* up = u + h * HD + kk * 16 + hi2 * 8;
            const float* vp = v + h * HD + kk * 16 + hi2 * 8;
#pragma unroll
            for (int m = 0; m < 8; ++m) {
                float qf = (float)q8[m];
                qu[kk][m] = (bf16)(qf + up[m]);
                qv[kk][m] = (bf16)(qf + vp[m]);
            }
        }
    }

    float mrun = -1e30f, lrun = 0.f;
    f32x16 o[2];
    o[0] = (f32x16){}; o[1] = (f32x16){};

    const int phq = (31 - ql) & 3;        // shear phase, lane-constant
    const int sel = phq >> 1;
    const int shb = (phq & 1) * 16;       // funnel-shift bits

    for (int tt = 0; tt < nt; ++tt) {
        const int j0 = tt * 64;

        __builtin_amdgcn_s_barrier();                 // A: prev tile's LDS reads done
        __builtin_amdgcn_sched_barrier(0);

        // ---- V store: transposed with jrot (compiler waits vreg via vmcnt) ----
#pragma unroll
        for (int p = 0; p < 2; ++p) {
            int j = p * 32 + rq;
#pragma unroll
            for (int mm = 0; mm < 8; ++mm)
                V_s[c8 * 8 + mm][(j + 8 * c8) & 63] = vreg[p][mm];
        }
        asm volatile("s_waitcnt vmcnt(0) lgkmcnt(0)" ::: "memory");
        __builtin_amdgcn_sched_barrier(0);
        __builtin_amdgcn_s_barrier();                 // B: K_s/V_s/P_s visible
        __builtin_amdgcn_sched_barrier(0);

        // ---- content scores S^T = K . QU^T (rows j, cols q) ----
        f32x16 st[2];
        st[0] = (f32x16){}; st[1] = (f32x16){};
        __builtin_amdgcn_s_setprio(1);
#pragma unroll
        for (int jt = 0; jt < 2; ++jt) {
            int row = jt * 32 + ql;
#pragma unroll
            for (int kk = 0; kk < 4; ++kk) {
                bf16x8 kf = *(const bf16x8*)&K_s[row * 64 + (((kk * 2 + hi2) ^ (ql & 7)) * 8)];
                st[jt] = MFMA32(kf, qu[kk], st[jt]);
            }
        }
        // ---- raw position scores: 96-row band, rows bw + Rt*32 + ql ----
        const int bwg = j0 - i0 + 480 - 32 * w;       // band base (>=0)
        f32x16 rp[3];
        rp[0] = (f32x16){}; rp[1] = (f32x16){}; rp[2] = (f32x16){};
#pragma unroll
        for (int Rt = 0; Rt < 3; ++Rt) {
            int ring = (bwg + Rt * 32 + ql) & 255;
#pragma unroll
            for (int kk = 0; kk < 4; ++kk) {
                bf16x8 pf = *(const bf16x8*)&P_s[ring * 64 + (((kk * 2 + hi2) ^ (ring & 7)) * 8)];
                rp[Rt] = MFMA32(pf, qv[kk], rp[Rt]);
            }
        }
        __builtin_amdgcn_s_setprio(0);

        __builtin_amdgcn_s_barrier();                 // C: all K/P reads retired
        __builtin_amdgcn_sched_barrier(0);

        // ---- prefetch next tile (issue-only; consumed at next A/B) ----
        if (tt + 1 < nt) {
            const int j0n = j0 + 64;
#pragma unroll
            for (int p = 0; p < 2; ++p)
                vreg[p] = *(const bf16x8*)(kv + (size_t)((j0n + p * 32 + rq) * BSZ + b) * 2048 + 1024 + h * HD + c8 * 8);
#pragma unroll
            for (int p = 0; p < 2; ++p)
                GLOAD16(kv + (size_t)((j0n + p * 32 + rq) * BSZ + b) * 2048 + h * HD + ((c8 ^ (rq & 7)) * 8),
                        K_s + (p * 32 + rq) * 64 + c8 * 8);
        }
        if (tt + 3 < nt) {
            const int Cs = C0 + (tt + 3) * 64;        // next chunk (rows <= 1023)
#pragma unroll
            for (int p = 0; p < 2; ++p) {
                int grow = Cs + p * 32 + rq;
                GLOAD16(pb + (size_t)grow * DIN + h * HD + ((c8 ^ (rq & 7)) * 8),
                        P_s + (grow & 255) * 64 + c8 * 8);
            }
        }

        // ---- rscT stores: 12 aligned b64 (quad = 4 consecutive C-rows) ----
#pragma unroll
        for (int Rt = 0; Rt < 3; ++Rt)
#pragma unroll
            for (int a = 0; a < 4; ++a) {
                u32 lo = (u32)bfbits(rp[Rt][a * 4 + 0]) | ((u32)bfbits(rp[Rt][a * 4 + 1]) << 16);
                u32 hi = (u32)bfbits(rp[Rt][a * 4 + 2]) | ((u32)bfbits(rp[Rt][a * 4 + 3]) << 16);
                *(u32x2*)(rsc + ql * 216 + 64 * Rt + 16 * a + 8 * hi2) = (u32x2){lo, hi};
            }

        // ---- assemble: sv = (content + shifted-pos)*scale, mask, rowmax ----
        float rowmax = -1e30f;
        const int limb = i0 + 32 * w + ql + PREV - j0;    // mask iff lj > limb
#pragma unroll
        for (int jt = 0; jt < 2; ++jt)
#pragma unroll
            for (int a = 0; a < 4; ++a) {
                int e = jt * 32 + 8 * a + 4 * hi2 + 31 - ql;      // [0,94]
                const u32x2* W = (const u32x2*)(rsc + ql * 216 + 8 * (e >> 2));
                u32x2 A0 = W[0], A1 = W[1];
                u32 U0 = sel ? A0[1] : A0[0];
                u32 U1 = sel ? A1[0] : A0[1];
                u32 U2 = sel ? A1[1] : A1[0];
                u32 o0 = (u32)((((unsigned long long)U1 << 32) | U0) >> shb);
                u32 o1 = (u32)((((unsigned long long)U2 << 32) | U1) >> shb);
                float pv0 = bf2f(o0 & 0xffffu), pv1 = bf2f(o0 >> 16);
                float pv2 = bf2f(o1 & 0xffffu), pv3 = bf2f(o1 >> 16);
                float pq[4] = {pv0, pv1, pv2, pv3};
#pragma unroll
                for (int rr = 0; rr < 4; ++rr) {
                    int r = a * 4 + rr;
                    int lj = jt * 32 + 8 * a + 4 * hi2 + rr;
                    float sv = (st[jt][r] + pq[rr]) * 0.125f;
                    if (lj > limb) sv = -1e30f;
                    st[jt][r] = sv;
                    rowmax = fmaxf(rowmax, sv);
                }
            }
        rowmax = fmaxf(rowmax, __shfl_xor(rowmax, 32));

        // ---- defer-max online softmax (q = ql per lane) ----
        if (!__all(rowmax - mrun <= 8.f)) {
            float newm = fmaxf(mrun, rowmax);
            float fsc = __expf(mrun - newm);
#pragma unroll
            for (int r = 0; r < 16; ++r) {
                float fr = __shfl(fsc, (r & 3) + 8 * (r >> 2) + 4 * hi2);
                o[0][r] *= fr; o[1][r] *= fr;
            }
            lrun *= fsc;
            mrun = newm;
        }
        float rowsum = 0.f;
#pragma unroll
        for (int jt = 0; jt < 2; ++jt)
#pragma unroll
            for (int r = 0; r < 16; ++r) {
                float p = __expf(st[jt][r] - mrun);
                st[jt][r] = p;
                rowsum += p;
            }
        rowsum += __shfl_xor(rowsum, 32);
        lrun += rowsum;

        // ---- probs -> ps (overlays rscT; ordered by data dependency) ----
#pragma unroll
        for (int jt = 0; jt < 2; ++jt)
#pragma unroll
            for (int a = 0; a < 4; ++a) {
                u32 lo = (u32)bfbits(st[jt][a * 4 + 0]) | ((u32)bfbits(st[jt][a * 4 + 1]) << 16);
                u32 hi = (u32)bfbits(st[jt][a * 4 + 2]) | ((u32)bfbits(st[jt][a * 4 + 3]) << 16);
                *(u32x2*)(ps + ql * 144 + 64 * jt + 16 * a + 8 * hi2) = (u32x2){lo, hi};
            }

        // ---- PV: O[q][d] += P . V ----
        __builtin_amdgcn_s_setprio(1);
#pragma unroll
        for (int js = 0; js < 4; ++js) {
            bf16x8 pa = *(const bf16x8*)(ps + ql * 144 + 32 * js + 16 * hi2);
#pragma unroll
            for (int dt = 0; dt < 2; ++dt) {
                int dcol = dt * 32 + ql;
                int colb = (js * 16 + hi2 * 8 + 8 * (dcol >> 3)) & 63;
                bf16x8 vf = *(const bf16x8*)&V_s[dcol][colb];
                o[dt] = MFMA32(pa, vf, o[dt]);
            }
        }
        __builtin_amdgcn_s_setprio(0);
    }

    // ---- epilogue: normalize (q lives in regs now) and store ----
    float lr[16];
#pragma unroll
    for (int r = 0; r < 16; ++r) lr[r] = __shfl(lrun, (r & 3) + 8 * (r >> 2) + 4 * hi2);
#pragma unroll
    for (int dt = 0; dt < 2; ++dt)
#pragma unroll
        for (int r = 0; r < 16; ++r) {
            int row = i0 + 32 * w + (r & 3) + 8 * (r >> 2) + 4 * hi2;
            awv[((size_t)row * BSZ + b) * DIN + h * HD + dt * 32 + ql] = (bf16)(o[dt][r] / lr[r]);
        }
}

// ---------------------------------------------------------------------------
// In-place LayerNorm over last dim (1024). One block per row.
// ---------------------------------------------------------------------------
__global__ __launch_bounds__(256) void ln_f32(
    float* __restrict__ out, const float* __restrict__ gamma, const float* __restrict__ beta)
{
    const int row = blockIdx.x;
    const int t = threadIdx.x;
    float4 x = *(float4*)(out + (size_t)row * DIN + t * 4);
    float s  = x.x + x.y + x.z + x.w;
    float ss = x.x * x.x + x.y * x.y + x.z * x.z + x.w * x.w;
#pragma unroll
    for (int wd = 1; wd < 64; wd <<= 1) { s += __shfl_xor(s, wd); ss += __shfl_xor(ss, wd); }
    __shared__ float sbuf[4], ssbuf[4];
    const int wave = t >> 6, lanei = t & 63;
    if (lanei == 0) { sbuf[wave] = s; ssbuf[wave] = ss; }
    __syncthreads();
    s  = sbuf[0] + sbuf[1] + sbuf[2] + sbuf[3];
    ss = ssbuf[0] + ssbuf[1] + ssbuf[2] + ssbuf[3];
    const float mu   = s * (1.f / DIN);
    const float var  = ss * (1.f / DIN) - mu * mu;
    const float rstd = rsqrtf(var + 1e-5f);
    float4 g  = *(const float4*)(gamma + t * 4);
    float4 bb = *(const float4*)(beta + t * 4);
    float4 y;
    y.x = (x.x - mu) * rstd * g.x + bb.x;
    y.y = (x.y - mu) * rstd * g.y + bb.y;
    y.z = (x.z - mu) * rstd * g.z + bb.z;
    y.w = (x.w - mu) * rstd * g.w + bb.w;
    *(float4*)(out + (size_t)row * DIN + t * 4) = y;
}

// ---------------------------------------------------------------------------
extern "C" void kernel_launch(void* const* d_in, const int* in_sizes, int n_in,
                              void* d_out, int out_size, void* d_ws, size_t ws_size,
                              hipStream_t stream)
{
    const float* input_ = (const float*)d_in[0];
    const float* pos    = (const float*)d_in[1];
    const float* memory = (const float*)d_in[2];
    const float* u      = (const float*)d_in[3];
    const float* v      = (const float*)d_in[4];
    // d_in[5] = mask: computed analytically (j > i + PREV)
    const float* W_kv   = (const float*)d_in[6];
    const float* W_q    = (const float*)d_in[7];
    const float* W_p    = (const float*)d_in[8];
    const float* W_out  = (const float*)d_in[9];
    const float* gamma  = (const float*)d_in[10];
    const float* beta   = (const float*)d_in[11];

    bf16* iwm  = (bf16*)d_ws;                      // [8192][1024]  (memory ; input)
    bf16* kvb  = iwm  + (size_t)8192 * 1024;       // [8192][2048]  k | v
    bf16* qbf  = kvb  + (size_t)8192 * 2048;       // [4096][1024]
    bf16* pbf  = qbf  + (size_t)4096 * 1024;       // [1024][1024]
    bf16* posb = pbf  + (size_t)1024 * 1024;       // [1024][1024]
    bf16* wkv  = posb + (size_t)1024 * 1024;       // [2048][1024]  W_kv^T
    bf16* wq   = wkv  + (size_t)2048 * 1024;       // [1024][1024]
    bf16* wp   = wq   + (size_t)1024 * 1024;
    bf16* wo   = wp   + (size_t)1024 * 1024;
    bf16* awvb = wo   + (size_t)1024 * 1024;       // [4096][1024]
    float* outf = (float*)d_out;

    // casts / transposes
    cast_cat<<<8192, 256, 0, stream>>>(memory, 4194304, input_, iwm);
    cast_cat<<<1024, 256, 0, stream>>>(pos, 1048576, pos, posb);
    transcast_all<<<dim3(160, 32), 256, 0, stream>>>(W_kv, W_q, W_p, W_out, wkv, wq, wp, wo);

    // projections (bf16 out)
    gemm_mfma<0><<<dim3(16, 64), 256, 0, stream>>>(iwm, wkv, nullptr, kvb, nullptr, 8192, 2048, 1024);
    gemm_mfma<0><<<dim3(8, 32), 256, 0, stream>>>(iwm + (size_t)4096 * 1024, wq, nullptr, qbf, nullptr, 4096, 1024, 1024);
    gemm_mfma<0><<<dim3(8, 8),  256, 0, stream>>>(posb, wp, nullptr, pbf, nullptr, 1024, 1024, 1024);

    // fused attention: 4 q-blocks x 8 b x 16 h, 256 threads (4 waves of 32 q)
    attn_mfma<<<dim3(4, 8, 16), 256, 0, stream>>>(kvb, qbf, pbf, u, v, awvb);

    // out projection + residual (f32), then LayerNorm
    gemm_mfma<1><<<dim3(8, 32), 256, 0, stream>>>(awvb, wo, input_, nullptr, outf, 4096, 1024, 1024);
    ln_f32<<<4096, 256, 0, stream>>>(outf, gamma, beta);
}